// Round 4
// baseline (1405.230 us; speedup 1.0000x reference)
//
#include <hip/hip_runtime.h>
#include <hip/hip_bf16.h>

typedef unsigned short u16;
typedef unsigned int   u32;
typedef short bf16x8 __attribute__((ext_vector_type(8)));
typedef float f32x4  __attribute__((ext_vector_type(4)));

#define DEV static __device__ __forceinline__

#define Bc 8
#define Lc 1024
#define Hc 1024
#define Ec 8
#define Ic 256
#define ISc 512
#define NHc 4
#define HDc 256
#define NTOK 8192
#define EPSc 1e-6f

DEV u16 f2bf(float f){
  u32 u = __float_as_uint(f);
  return (u16)((u + 0x7fffu + ((u >> 16) & 1u)) >> 16);
}
DEV float bf2f(u16 h){ return __uint_as_float(((u32)h) << 16); }

DEV void gload_lds16(const void* g, void* l){
  __builtin_amdgcn_global_load_lds((const __attribute__((address_space(1))) u32*)g,
                                   (__attribute__((address_space(3))) u32*)l, 16, 0, 0);
}

// ---------------------------------------------------------------------------
// Split-precision NT GEMM: C = (Ahi+Alo)·(Bhi+Blo)^T ≈ AhiBhi + AhiBlo + AloBhi
// EPI: 0 = packed hi|lo u16 store (lo at +loOffC), 1 = f32 store,
//      2 = f32 = acc + bias + Res, 3 = V-transpose packed hi|lo (QKV V part)
// ---------------------------------------------------------------------------
template<int EPI, bool BIAS>
__global__ __launch_bounds__(256)
void gemm3(const u16* __restrict__ Ahi, const u16* __restrict__ Alo,
           const u16* __restrict__ Bhi, const u16* __restrict__ Blo,
           void* __restrict__ Cv, const float* __restrict__ bias,
           const float* __restrict__ Res,
           int M, int N, int K, int lda, int ldb, int ldc,
           long sAz, long sBz, long sCz, int loOffC)
{
  __shared__ u16 lsAh[128*32];
  __shared__ u16 lsAl[128*32];
  __shared__ u16 lsBh[128*32];
  __shared__ u16 lsBl[128*32];
  const int z = blockIdx.z;
  const u16* Ahb = Ahi + (long)z*sAz;
  const u16* Alb = Alo + (long)z*sAz;
  const u16* Bhb = Bhi + (long)z*sBz;
  const u16* Blb = Blo + (long)z*sBz;
  const int n0 = blockIdx.x*128, m0 = blockIdx.y*128;
  const int t = threadIdx.x, lane = t & 63;
  const int w = t >> 6, wm = w >> 1, wn = w & 1;
  const int fr = lane & 15, kg = lane >> 4;
  const int srow = t >> 2, scol = (t & 3) * 8;
  f32x4 acc[4][4] = {};

  for (int kb = 0; kb < K; kb += 32){
    gload_lds16(Ahb + (long)(m0 +      srow)*lda + kb + scol, &lsAh[srow*32 + scol]);
    gload_lds16(Ahb + (long)(m0 + 64 + srow)*lda + kb + scol, &lsAh[(64+srow)*32 + scol]);
    gload_lds16(Alb + (long)(m0 +      srow)*lda + kb + scol, &lsAl[srow*32 + scol]);
    gload_lds16(Alb + (long)(m0 + 64 + srow)*lda + kb + scol, &lsAl[(64+srow)*32 + scol]);
    gload_lds16(Bhb + (long)(n0 +      srow)*ldb + kb + scol, &lsBh[srow*32 + scol]);
    gload_lds16(Bhb + (long)(n0 + 64 + srow)*ldb + kb + scol, &lsBh[(64+srow)*32 + scol]);
    gload_lds16(Blb + (long)(n0 +      srow)*ldb + kb + scol, &lsBl[srow*32 + scol]);
    gload_lds16(Blb + (long)(n0 + 64 + srow)*ldb + kb + scol, &lsBl[(64+srow)*32 + scol]);
    asm volatile("s_waitcnt vmcnt(0)" ::: "memory");
    __syncthreads();
    bf16x8 ah[4], al[4], bh[4], bl[4];
#pragma unroll
    for (int i = 0; i < 4; i++){
      ah[i] = *(const bf16x8*)&lsAh[(wm*64 + i*16 + fr)*32 + kg*8];
      al[i] = *(const bf16x8*)&lsAl[(wm*64 + i*16 + fr)*32 + kg*8];
      bh[i] = *(const bf16x8*)&lsBh[(wn*64 + i*16 + fr)*32 + kg*8];
      bl[i] = *(const bf16x8*)&lsBl[(wn*64 + i*16 + fr)*32 + kg*8];
    }
#pragma unroll
    for (int mi = 0; mi < 4; mi++)
#pragma unroll
      for (int ni = 0; ni < 4; ni++){
        acc[mi][ni] = __builtin_amdgcn_mfma_f32_16x16x32_bf16(ah[mi], bh[ni], acc[mi][ni], 0, 0, 0);
        acc[mi][ni] = __builtin_amdgcn_mfma_f32_16x16x32_bf16(ah[mi], bl[ni], acc[mi][ni], 0, 0, 0);
        acc[mi][ni] = __builtin_amdgcn_mfma_f32_16x16x32_bf16(al[mi], bh[ni], acc[mi][ni], 0, 0, 0);
      }
    __syncthreads();
  }

  const int r4 = (lane >> 4) * 4;
#pragma unroll
  for (int mi = 0; mi < 4; mi++){
#pragma unroll
    for (int ni = 0; ni < 4; ni++){
      const int col = n0 + wn*64 + ni*16 + fr;
      const float bb = BIAS ? bias[col] : 0.f;
#pragma unroll
      for (int r = 0; r < 4; r++){
        const int row = m0 + wm*64 + mi*16 + r4 + r;
        float v = acc[mi][ni][r] + bb;
        if (EPI == 0){
          u16 hv = f2bf(v), lv = f2bf(v - bf2f(hv));
          long idx = (long)z*sCz + (long)row*ldc + col;
          ((u16*)Cv)[idx] = hv;
          ((u16*)Cv)[idx + loOffC] = lv;
        } else if (EPI == 1){
          ((float*)Cv)[(long)z*sCz + (long)row*ldc + col] = v;
        } else if (EPI == 2){
          long idx = (long)z*sCz + (long)row*ldc + col;
          ((float*)Cv)[idx] = v + Res[idx];
        } else {                      // EPI==3: V transpose, packed hi|lo
          u16 hv = f2bf(v), lv = f2bf(v - bf2f(hv));
          int b = row >> 10, q = row & 1023;
          int h = col >> 8, d = col & 255;
          long o = ((long)(b*NHc + h)*HDc + d)*2048 + q;
          ((u16*)Cv)[o] = hv;
          ((u16*)Cv)[o + 1024] = lv;
        }
      }
    }
  }
}

// ---------------------------------------------------------------------------
// Plain bf16 NT GEMM (m97 structure) for the MoE path.
// EPI: 0 = store bf16, 1 = store f32, 2 = f32 +=
template<int EPI>
__global__ __launch_bounds__(256)
void gemm_bt(const u16* __restrict__ A, const u16* __restrict__ B,
             void* __restrict__ Cv,
             int M, int N, int K, int lda, int ldb, int ldc)
{
  __shared__ u16 lsA[128*32];
  __shared__ u16 lsB[128*32];
  const int n0 = blockIdx.x*128, m0 = blockIdx.y*128;
  const int t = threadIdx.x, lane = t & 63;
  const int w = t >> 6, wm = w >> 1, wn = w & 1;
  const int fr = lane & 15, kg = lane >> 4;
  const int srow = t >> 2, scol = (t & 3) * 8;
  f32x4 acc[4][4] = {};

  for (int kb = 0; kb < K; kb += 32){
    gload_lds16(A + (long)(m0 +      srow)*lda + kb + scol, &lsA[srow*32 + scol]);
    gload_lds16(A + (long)(m0 + 64 + srow)*lda + kb + scol, &lsA[(64+srow)*32 + scol]);
    gload_lds16(B + (long)(n0 +      srow)*ldb + kb + scol, &lsB[srow*32 + scol]);
    gload_lds16(B + (long)(n0 + 64 + srow)*ldb + kb + scol, &lsB[(64+srow)*32 + scol]);
    asm volatile("s_waitcnt vmcnt(0)" ::: "memory");
    __syncthreads();
    bf16x8 av[4], bv[4];
#pragma unroll
    for (int i = 0; i < 4; i++){
      av[i] = *(const bf16x8*)&lsA[(wm*64 + i*16 + fr)*32 + kg*8];
      bv[i] = *(const bf16x8*)&lsB[(wn*64 + i*16 + fr)*32 + kg*8];
    }
#pragma unroll
    for (int mi = 0; mi < 4; mi++)
#pragma unroll
      for (int ni = 0; ni < 4; ni++)
        acc[mi][ni] = __builtin_amdgcn_mfma_f32_16x16x32_bf16(av[mi], bv[ni], acc[mi][ni], 0, 0, 0);
    __syncthreads();
  }

  const int r4 = (lane >> 4) * 4;
#pragma unroll
  for (int mi = 0; mi < 4; mi++){
#pragma unroll
    for (int ni = 0; ni < 4; ni++){
      const int col = n0 + wn*64 + ni*16 + fr;
#pragma unroll
      for (int r = 0; r < 4; r++){
        const int row = m0 + wm*64 + mi*16 + r4 + r;
        const long idx = (long)row*ldc + col;
        float v = acc[mi][ni][r];
        if      (EPI == 0) ((u16*)Cv)[idx]   = f2bf(v);
        else if (EPI == 1) ((float*)Cv)[idx] = v;
        else               ((float*)Cv)[idx] += v;
      }
    }
  }
}

// ---------------------------------------------------------------------------
__global__ void cast_bf16_k(const float* __restrict__ in, u16* __restrict__ out, long n){
  long i = (long)blockIdx.x*blockDim.x + threadIdx.x;
  long st = (long)gridDim.x*blockDim.x;
  for (; i < n; i += st) out[i] = f2bf(in[i]);
}

__global__ void split_cast_k(const float* __restrict__ in, u16* __restrict__ hi,
                             u16* __restrict__ lo, long n){
  long i = (long)blockIdx.x*blockDim.x + threadIdx.x;
  long st = (long)gridDim.x*blockDim.x;
  for (; i < n; i += st){
    float v = in[i];
    u16 h = f2bf(v);
    hi[i] = h;
    lo[i] = f2bf(v - bf2f(h));
  }
}

// routed gate/up folded with expert_norm_w: wgu[e][i][h]=g*nw, wgu[e][256+i][h]=u*nw
__global__ void fold_expert_k(const float* __restrict__ g, const float* __restrict__ u,
                              const float* __restrict__ nw, u16* __restrict__ gu, long n){
  long i = (long)blockIdx.x*blockDim.x + threadIdx.x;
  long st = (long)gridDim.x*blockDim.x;
  for (; i < n; i += st){
    int h  = (int)(i & (Hc - 1));
    int ii = (int)((i >> 10) & (Ic - 1));
    int e  = (int)(i >> 18);
    float wv = nw[e*Hc + h];
    long o = (long)e*(2*Ic*Hc) + (long)ii*Hc + h;
    gu[o]         = f2bf(g[i]*wv);
    gu[o + Ic*Hc] = f2bf(u[i]*wv);
  }
}

// rmsnorm -> packed hi|lo u16 rows [row][2048]
__global__ __launch_bounds__(256)
void rmsnorm_split_k(const float* __restrict__ x, const float* __restrict__ w1,
                     u16* __restrict__ o){
  const int row = blockIdx.x, t = threadIdx.x, lane = t & 63, w = t >> 6;
  float4 v = ((const float4*)(x + (long)row*Hc))[t];
  float ss = v.x*v.x + v.y*v.y + v.z*v.z + v.w*v.w;
  for (int off = 32; off; off >>= 1) ss += __shfl_xor(ss, off);
  __shared__ float red[4];
  if (lane == 0) red[w] = ss;
  __syncthreads();
  float rs = rsqrtf((red[0]+red[1]+red[2]+red[3])*(1.f/Hc) + EPSc);
  float4 wv = ((const float4*)w1)[t];
  float f0 = v.x*rs*wv.x, f1 = v.y*rs*wv.y, f2 = v.z*rs*wv.z, f3 = v.w*rs*wv.w;
  ushort4 hv, lv;
  hv.x = f2bf(f0); lv.x = f2bf(f0 - bf2f(hv.x));
  hv.y = f2bf(f1); lv.y = f2bf(f1 - bf2f(hv.y));
  hv.z = f2bf(f2); lv.z = f2bf(f2 - bf2f(hv.z));
  hv.w = f2bf(f3); lv.w = f2bf(f3 - bf2f(hv.w));
  u16* r16 = o + (long)row*2048;
  ((ushort4*)r16)[t] = hv;
  ((ushort4*)(r16 + 1024))[t] = lv;
}

// rmsnorm -> two plain bf16 outputs (xhat with w=1, sx with shared_norm_w)
__global__ __launch_bounds__(256)
void rmsnorm_k(const float* __restrict__ x, u16* __restrict__ o1,
               const float* __restrict__ w2, u16* __restrict__ o2){
  const int row = blockIdx.x, t = threadIdx.x, lane = t & 63, w = t >> 6;
  float4 v = ((const float4*)(x + (long)row*Hc))[t];
  float ss = v.x*v.x + v.y*v.y + v.z*v.z + v.w*v.w;
  for (int off = 32; off; off >>= 1) ss += __shfl_xor(ss, off);
  __shared__ float red[4];
  if (lane == 0) red[w] = ss;
  __syncthreads();
  float rs = rsqrtf((red[0]+red[1]+red[2]+red[3])*(1.f/Hc) + EPSc);
  ushort4 ov;
  ov.x = f2bf(v.x*rs); ov.y = f2bf(v.y*rs); ov.z = f2bf(v.z*rs); ov.w = f2bf(v.w*rs);
  ((ushort4*)o1)[(long)row*256 + t] = ov;
  float4 wv = ((const float4*)w2)[t];
  ov.x = f2bf(v.x*rs*wv.x); ov.y = f2bf(v.y*rs*wv.y);
  ov.z = f2bf(v.z*rs*wv.z); ov.w = f2bf(v.w*rs*wv.w);
  ((ushort4*)o2)[(long)row*256 + t] = ov;
}

// masked softmax over f32 S rows; writes packed hi|lo P in place (u16 [0..1024)|[1024..2048))
__global__ __launch_bounds__(256)
void softmax2_k(float* __restrict__ S, const int* __restrict__ cnt, int bbase){
  const int rid = blockIdx.x;
  const int b = bbase + (rid >> 10);
  float* row = S + (long)rid*Lc;
  const int n = cnt[b];
  const int t = threadIdx.x, lane = t & 63, w = t >> 6;
  float4 v = ((const float4*)row)[t];
  const float sc = 0.0625f;
  float vals[4] = {v.x*sc, v.y*sc, v.z*sc, v.w*sc};
  const int c = t*4;
  float m = -3.4e38f;
#pragma unroll
  for (int j = 0; j < 4; j++) if (c + j < n) m = fmaxf(m, vals[j]);
  for (int o = 32; o; o >>= 1) m = fmaxf(m, __shfl_xor(m, o));
  __shared__ float red[8];
  if (lane == 0) red[w] = m;
  __syncthreads();
  m = fmaxf(fmaxf(red[0], red[1]), fmaxf(red[2], red[3]));
  float p[4], s = 0.f;
#pragma unroll
  for (int j = 0; j < 4; j++){ p[j] = (c + j < n) ? __expf(vals[j] - m) : 0.f; s += p[j]; }
  for (int o = 32; o; o >>= 1) s += __shfl_xor(s, o);
  if (lane == 0) red[4 + w] = s;
  __syncthreads();
  const float inv = 1.f / (red[4]+red[5]+red[6]+red[7]);
  ushort4 hv, lv;
  float q0 = p[0]*inv, q1 = p[1]*inv, q2 = p[2]*inv, q3 = p[3]*inv;
  hv.x = f2bf(q0); lv.x = f2bf(q0 - bf2f(hv.x));
  hv.y = f2bf(q1); lv.y = f2bf(q1 - bf2f(hv.y));
  hv.z = f2bf(q2); lv.z = f2bf(q2 - bf2f(hv.z));
  hv.w = f2bf(q3); lv.w = f2bf(q3 - bf2f(hv.w));
  u16* r16 = (u16*)S + (long)rid*2048;
  ((ushort4*)r16)[t] = hv;
  ((ushort4*)(r16 + 1024))[t] = lv;
}

// gating: one wave per token, f32
__global__ __launch_bounds__(256)
void gating_k(const float* __restrict__ x, const float* __restrict__ gnw,
              const float* __restrict__ gw, int* __restrict__ topi, float* __restrict__ topw){
  const int t = threadIdx.x, lane = t & 63, w = t >> 6;
  const int n = blockIdx.x*4 + w;
  const float* xr = x + (long)n*Hc;
  float ss = 0.f, sc[8] = {0,0,0,0,0,0,0,0};
  for (int j = 0; j < 16; j++){
    int d = j*64 + lane;
    float xv = xr[d];
    ss += xv*xv;
    float xg = xv * gnw[d];
#pragma unroll
    for (int e = 0; e < 8; e++) sc[e] += xg * gw[e*Hc + d];
  }
  for (int o = 32; o; o >>= 1){
    ss += __shfl_xor(ss, o);
#pragma unroll
    for (int e = 0; e < 8; e++) sc[e] += __shfl_xor(sc[e], o);
  }
  float rs = rsqrtf(ss*(1.f/Hc) + EPSc);
  float m = -3.4e38f;
#pragma unroll
  for (int e = 0; e < 8; e++){ sc[e] *= rs; m = fmaxf(m, sc[e]); }
  float p[8], sum = 0.f;
#pragma unroll
  for (int e = 0; e < 8; e++){ p[e] = __expf(sc[e] - m); sum += p[e]; }
  float inv = 1.f/sum;
#pragma unroll
  for (int e = 0; e < 8; e++) p[e] *= inv;
  int i1 = 0; float v1 = p[0];
#pragma unroll
  for (int e = 1; e < 8; e++) if (p[e] > v1){ v1 = p[e]; i1 = e; }
  int i2 = -1; float v2 = -1.f;
#pragma unroll
  for (int e = 0; e < 8; e++) if (e != i1 && p[e] > v2){ v2 = p[e]; i2 = e; }
  if (lane == 0){
    float dn = v1 + v2 + 1e-20f;
    topi[2*n] = i1; topi[2*n + 1] = i2;
    topw[2*n] = v1/dn; topw[2*n + 1] = v2/dn;
  }
}

__global__ void act_shared_k(const u16* __restrict__ gu, u16* __restrict__ z, long n){
  long i = (long)blockIdx.x*blockDim.x + threadIdx.x;
  long st = (long)gridDim.x*blockDim.x;
  for (; i < n; i += st){
    long nn = i >> 9;
    int  ii = (int)(i & (ISc - 1));
    float gv = bf2f(gu[nn*1024 + ii]);
    float uv = bf2f(gu[nn*1024 + ISc + ii]);
    z[i] = f2bf(gv/(1.f + __expf(-gv)) * uv);
  }
}

__global__ void act_expert_k(const u16* __restrict__ gu, const int* __restrict__ topi,
                             const float* __restrict__ topw, int e,
                             u16* __restrict__ z, long n){
  long i = (long)blockIdx.x*blockDim.x + threadIdx.x;
  long st = (long)gridDim.x*blockDim.x;
  for (; i < n; i += st){
    long nn = i >> 8;
    int  ii = (int)(i & (Ic - 1));
    float wv = 0.f;
    if      (topi[2*nn]     == e) wv = topw[2*nn];
    else if (topi[2*nn + 1] == e) wv = topw[2*nn + 1];
    float gv = bf2f(gu[nn*512 + ii]);
    float uv = bf2f(gu[nn*512 + Ic + ii]);
    z[i] = f2bf(gv/(1.f + __expf(-gv)) * uv * wv);
  }
}

__global__ __launch_bounds__(256)
void final_k(const float* __restrict__ y, const float* __restrict__ ogw,
             const float* __restrict__ ogb, const int* __restrict__ cnt,
             float* __restrict__ out){
  const int t = threadIdx.x, lane = t & 63, w = t >> 6;
  const int n = blockIdx.x*4 + w;
  const int b = n >> 10, l = n & 1023;
  const bool pad = l >= cnt[b];
  const float* yr = y + (long)n*Hc;
  float dot = 0.f, yv[16];
#pragma unroll
  for (int j = 0; j < 16; j++){
    int d = j*64 + lane;
    yv[j] = yr[d];
    dot += yv[j]*ogw[d];
  }
  for (int o = 32; o; o >>= 1) dot += __shfl_xor(dot, o);
  float s = 1.f/(1.f + __expf(-(dot + ogb[0])));
  float* outr = out + (long)n*Hc;
#pragma unroll
  for (int j = 0; j < 16; j++){
    int d = j*64 + lane;
    outr[d] = pad ? 0.f : yv[j]*s;
  }
}

__global__ void sentinel_k(float* out){ out[0] = 1.0e9f; }

// ---------------------------------------------------------------------------
extern "C" void kernel_launch(void* const* d_in, const int* in_sizes, int n_in,
                              void* d_out, int out_size, void* d_ws, size_t ws_size,
                              hipStream_t stream){
  const float* hidden  = (const float*)d_in[0];
  const int*   cnt     = (const int*)  d_in[1];
  const float* ctx_nw  = (const float*)d_in[2];
  const float* Wqkv    = (const float*)d_in[3];
  const float* in_b    = (const float*)d_in[4];
  const float* Woutp   = (const float*)d_in[5];
  const float* out_b   = (const float*)d_in[6];
  const float* gate_nw = (const float*)d_in[7];
  const float* gate_w  = (const float*)d_in[8];
  const float* exp_nw  = (const float*)d_in[9];
  const float* Weg     = (const float*)d_in[10];
  const float* Weu     = (const float*)d_in[11];
  const float* Wed     = (const float*)d_in[12];
  const float* sh_nw   = (const float*)d_in[13];
  const float* Wsg     = (const float*)d_in[14];
  const float* Wsu     = (const float*)d_in[15];
  const float* Wsd     = (const float*)d_in[16];
  const float* ogw     = (const float*)d_in[17];
  const float* ogb     = (const float*)d_in[18];
  float* out = (float*)d_out;

  const size_t MB = 1024*1024;
  char* ws = (char*)d_ws;
  size_t off = 0;
  auto alloc = [&](size_t bytes)->char*{
    char* p = ws + off; off += (bytes + 255) & ~(size_t)255; return p;
  };
  // weights
  u16* wWqH  = (u16*)alloc((size_t)3072*1024*2);   // qkv hi plane
  u16* wWqL  = (u16*)alloc((size_t)3072*1024*2);   // qkv lo plane
  u16* wWoH  = (u16*)alloc((size_t)1024*1024*2);
  u16* wWoL  = (u16*)alloc((size_t)1024*1024*2);
  u16* wWgu  = (u16*)alloc((size_t)Ec*2*Ic*Hc*2);  // routed gate|up (norm folded)
  u16* wWd   = (u16*)alloc((size_t)Ec*Hc*Ic*2);
  u16* wWsgu = (u16*)alloc((size_t)2*ISc*Hc*2);    // shared gate|up
  u16* wWsd  = (u16*)alloc((size_t)Hc*ISc*2);
  int*   wTopI = (int*)  alloc((size_t)NTOK*2*4);
  float* wTopW = (float*)alloc((size_t)NTOK*2*4);
  // arenas (lifetime overlaid)
  char* P1 = alloc(32*MB);   // nx packed -> ctx packed -> Y f32
  char* P2 = alloc(32*MB);   // Qp packed -> Xhat bf16 + Sx bf16
  char* P3 = alloc(32*MB);   // Kp packed -> X f32 -> expGU + Ze
  char* P4 = alloc(32*MB);   // Vtp packed -> shGU + Zs
  char* P5 = alloc(16*MB);   // S f32 (4 batches x 1024 x 1024)
  if (off > ws_size){ sentinel_k<<<1,1,0,stream>>>(out); return; }

  u16*   wNx   = (u16*)P1;               // [NTOK][2048] hi|lo
  u16*   wCtx  = (u16*)P1;               // [NTOK][2048] hi|lo (after QKV)
  float* wY    = (float*)P1;             // [NTOK][1024] f32 (after out-proj)
  u16*   wQp   = (u16*)P2;               // [NTOK][2048] hi|lo
  u16*   wXhat = (u16*)P2;               // [NTOK][1024] bf16
  u16*   wSx   = (u16*)(P2 + 16*MB);     // [NTOK][1024] bf16
  u16*   wKp   = (u16*)P3;               // [NTOK][2048] hi|lo
  float* wX    = (float*)P3;             // [NTOK][1024] f32
  u16*   wGUe  = (u16*)P3;               // [NTOK][512] per-expert (after X consumed)
  u16*   wZe   = (u16*)(P3 + 8*MB);      // [NTOK][256]
  u16*   wVtp  = (u16*)P4;               // [B*NH][HD][2048] q-hi|q-lo
  u16*   wGUs  = (u16*)P4;               // [NTOK][1024] shared gate|up
  u16*   wZs   = (u16*)(P4 + 16*MB);     // [NTOK][512]
  float* wS    = (float*)P5;             // [4][1024][1024] f32 -> P hi|lo packed

  // 1) weight prep
  split_cast_k<<<4096, 256, 0, stream>>>(Wqkv,  wWqH, wWqL, (long)3072*1024);
  split_cast_k<<<2048, 256, 0, stream>>>(Woutp, wWoH, wWoL, (long)1024*1024);
  cast_bf16_k<<<2048, 256, 0, stream>>>(Wed, wWd, (long)Ec*Hc*Ic);
  cast_bf16_k<<<1024, 256, 0, stream>>>(Wsg, wWsgu,                (long)ISc*Hc);
  cast_bf16_k<<<1024, 256, 0, stream>>>(Wsu, wWsgu + (long)ISc*Hc, (long)ISc*Hc);
  cast_bf16_k<<<1024, 256, 0, stream>>>(Wsd, wWsd, (long)Hc*ISc);
  fold_expert_k<<<2048, 256, 0, stream>>>(Weg, Weu, exp_nw, wWgu, (long)Ec*Ic*Hc);

  // 2) pre-attn norm (split) + Q/K/V projections (split precision)
  rmsnorm_split_k<<<NTOK, 256, 0, stream>>>(hidden, ctx_nw, wNx);
  gemm3<0, true><<<dim3(8, 64, 1), 256, 0, stream>>>(
      wNx, wNx + 1024, wWqH, wWqL, wQp, in_b, nullptr,
      NTOK, 1024, 1024, 2048, 1024, 2048, 0, 0, 0, 1024);
  gemm3<0, true><<<dim3(8, 64, 1), 256, 0, stream>>>(
      wNx, wNx + 1024, wWqH + (long)1024*1024, wWqL + (long)1024*1024, wKp,
      in_b + 1024, nullptr, NTOK, 1024, 1024, 2048, 1024, 2048, 0, 0, 0, 1024);
  gemm3<3, true><<<dim3(8, 64, 1), 256, 0, stream>>>(
      wNx, wNx + 1024, wWqH + (long)2048*1024, wWqL + (long)2048*1024, wVtp,
      in_b + 2048, nullptr, NTOK, 1024, 1024, 2048, 1024, 0, 0, 0, 0, 0);

  // 3) attention: per head x per 4-batch half (split precision)
  for (int h = 0; h < NHc; h++){
    for (int hf = 0; hf < 2; hf++){
      const u16* Qb = wQp + (long)hf*4*Lc*2048 + h*HDc;
      const u16* Kb = wKp + (long)hf*4*Lc*2048 + h*HDc;
      gemm3<1, false><<<dim3(8, 8, 4), 256, 0, stream>>>(
          Qb, Qb + 1024, Kb, Kb + 1024, wS, nullptr, nullptr,
          Lc, Lc, HDc, 2048, 2048, Lc,
          (long)Lc*2048, (long)Lc*2048, (long)Lc*Lc, 0);
      softmax2_k<<<4096, 256, 0, stream>>>(wS, cnt, hf*4);
      // FIX (round 3 bug): V batch base must include the hf half offset.
      const u16* Vb = wVtp + ((long)hf*4*NHc + h)*HDc*2048;
      u16* Cb = wCtx + (long)hf*4*Lc*2048 + h*HDc;
      gemm3<0, false><<<dim3(2, 8, 4), 256, 0, stream>>>(
          (const u16*)wS, (const u16*)wS + 1024, Vb, Vb + 1024, Cb, nullptr, nullptr,
          Lc, HDc, Lc, 2048, 2048, 2048,
          (long)Lc*2048, (long)NHc*HDc*2048, (long)Lc*2048, 1024);
    }
  }

  // 4) out-proj + bias + residual -> X f32 (split precision)
  gemm3<2, true><<<dim3(8, 64, 1), 256, 0, stream>>>(
      wCtx, wCtx + 1024, wWoH, wWoL, wX, out_b, hidden,
      NTOK, 1024, 1024, 2048, 1024, 1024, 0, 0, 0, 0);

  // 5) gating (f32, from accurate X) + post-norms
  gating_k<<<NTOK/4, 256, 0, stream>>>(wX, gate_nw, gate_w, wTopI, wTopW);
  rmsnorm_k<<<NTOK, 256, 0, stream>>>(wX, wXhat, sh_nw, wSx);

  // 6) shared experts -> Y (bf16 GEMMs)
  gemm_bt<0><<<dim3(8, 64, 1), 256, 0, stream>>>(
      wSx, wWsgu, wGUs, NTOK, 2*ISc, 1024, 1024, 1024, 2*ISc);
  act_shared_k<<<4096, 256, 0, stream>>>(wGUs, wZs, (long)NTOK*ISc);
  gemm_bt<1><<<dim3(8, 64, 1), 256, 0, stream>>>(
      wZs, wWsd, wY, NTOK, 1024, ISc, ISc, ISc, 1024);

  // 7) routed experts, one at a time -> Y +=
  for (int e = 0; e < Ec; e++){
    gemm_bt<0><<<dim3(4, 64, 1), 256, 0, stream>>>(
        wXhat, wWgu + (long)e*2*Ic*Hc, wGUe, NTOK, 2*Ic, 1024, 1024, 1024, 2*Ic);
    act_expert_k<<<2048, 256, 0, stream>>>(wGUe, wTopI, wTopW, e, wZe, (long)NTOK*Ic);
    gemm_bt<2><<<dim3(8, 64, 1), 256, 0, stream>>>(
        wZe, wWd + (long)e*Hc*Ic, wY, NTOK, 1024, Ic, Ic, Ic, 1024);
  }

  // 8) out gate + padding mask
  final_k<<<NTOK/4, 256, 0, stream>>>(wY, ogw, ogb, cnt, out);
}

// Round 5
// 841.511 us; speedup vs baseline: 1.6699x; 1.6699x over previous
//
#include <hip/hip_runtime.h>
#include <hip/hip_bf16.h>

typedef unsigned short u16;
typedef unsigned int   u32;
typedef short bf16x8 __attribute__((ext_vector_type(8)));
typedef float f32x4  __attribute__((ext_vector_type(4)));

#define DEV static __device__ __forceinline__

#define Bc 8
#define Lc 1024
#define Hc 1024
#define Ec 8
#define Ic 256
#define ISc 512
#define NHc 4
#define HDc 256
#define NTOK 8192
#define EPSc 1e-6f

DEV u16 f2bf(float f){
  u32 u = __float_as_uint(f);
  return (u16)((u + 0x7fffu + ((u >> 16) & 1u)) >> 16);
}
DEV float bf2f(u16 h){ return __uint_as_float(((u32)h) << 16); }

DEV void gload_lds16(const void* g, void* l){
  __builtin_amdgcn_global_load_lds((const __attribute__((address_space(1))) u32*)g,
                                   (__attribute__((address_space(3))) u32*)l, 16, 0, 0);
}

// ---------------------------------------------------------------------------
// Split-precision NT GEMM: C = (Ahi+Alo)·(Bhi+Blo)^T ≈ AhiBhi + AhiBlo + AloBhi
// z decomposes as zin = z&3 (inner, e.g. batch), zout = z>>2 (outer, e.g. head)
// EPI: 0 = packed hi|lo u16 store (lo at +loOffC), 1 = f32 store,
//      2 = f32 = acc + bias + Res, 3 = V-transpose packed hi|lo (QKV V part)
// ---------------------------------------------------------------------------
template<int EPI, bool BIAS>
__global__ __launch_bounds__(256)
void gemm3(const u16* __restrict__ Ahi, const u16* __restrict__ Alo,
           const u16* __restrict__ Bhi, const u16* __restrict__ Blo,
           void* __restrict__ Cv, const float* __restrict__ bias,
           const float* __restrict__ Res,
           int M, int N, int K, int lda, int ldb, int ldc,
           long sAin, long sAout, long sBin, long sBout, long sCin, long sCout,
           int loOffC)
{
  __shared__ u16 lsAh[128*32];
  __shared__ u16 lsAl[128*32];
  __shared__ u16 lsBh[128*32];
  __shared__ u16 lsBl[128*32];
  const int z = blockIdx.z, zin = z & 3, zout = z >> 2;
  const long aoff = (long)zin*sAin + (long)zout*sAout;
  const long boff = (long)zin*sBin + (long)zout*sBout;
  const long coff = (long)zin*sCin + (long)zout*sCout;
  const u16* Ahb = Ahi + aoff;
  const u16* Alb = Alo + aoff;
  const u16* Bhb = Bhi + boff;
  const u16* Blb = Blo + boff;
  const int n0 = blockIdx.x*128, m0 = blockIdx.y*128;
  const int t = threadIdx.x, lane = t & 63;
  const int w = t >> 6, wm = w >> 1, wn = w & 1;
  const int fr = lane & 15, kg = lane >> 4;
  const int srow = t >> 2, scol = (t & 3) * 8;
  f32x4 acc[4][4] = {};

  for (int kb = 0; kb < K; kb += 32){
    gload_lds16(Ahb + (long)(m0 +      srow)*lda + kb + scol, &lsAh[srow*32 + scol]);
    gload_lds16(Ahb + (long)(m0 + 64 + srow)*lda + kb + scol, &lsAh[(64+srow)*32 + scol]);
    gload_lds16(Alb + (long)(m0 +      srow)*lda + kb + scol, &lsAl[srow*32 + scol]);
    gload_lds16(Alb + (long)(m0 + 64 + srow)*lda + kb + scol, &lsAl[(64+srow)*32 + scol]);
    gload_lds16(Bhb + (long)(n0 +      srow)*ldb + kb + scol, &lsBh[srow*32 + scol]);
    gload_lds16(Bhb + (long)(n0 + 64 + srow)*ldb + kb + scol, &lsBh[(64+srow)*32 + scol]);
    gload_lds16(Blb + (long)(n0 +      srow)*ldb + kb + scol, &lsBl[srow*32 + scol]);
    gload_lds16(Blb + (long)(n0 + 64 + srow)*ldb + kb + scol, &lsBl[(64+srow)*32 + scol]);
    asm volatile("s_waitcnt vmcnt(0)" ::: "memory");
    __syncthreads();
    bf16x8 ah[4], al[4], bh[4], bl[4];
#pragma unroll
    for (int i = 0; i < 4; i++){
      ah[i] = *(const bf16x8*)&lsAh[(wm*64 + i*16 + fr)*32 + kg*8];
      al[i] = *(const bf16x8*)&lsAl[(wm*64 + i*16 + fr)*32 + kg*8];
      bh[i] = *(const bf16x8*)&lsBh[(wn*64 + i*16 + fr)*32 + kg*8];
      bl[i] = *(const bf16x8*)&lsBl[(wn*64 + i*16 + fr)*32 + kg*8];
    }
#pragma unroll
    for (int mi = 0; mi < 4; mi++)
#pragma unroll
      for (int ni = 0; ni < 4; ni++){
        acc[mi][ni] = __builtin_amdgcn_mfma_f32_16x16x32_bf16(ah[mi], bh[ni], acc[mi][ni], 0, 0, 0);
        acc[mi][ni] = __builtin_amdgcn_mfma_f32_16x16x32_bf16(ah[mi], bl[ni], acc[mi][ni], 0, 0, 0);
        acc[mi][ni] = __builtin_amdgcn_mfma_f32_16x16x32_bf16(al[mi], bh[ni], acc[mi][ni], 0, 0, 0);
      }
    __syncthreads();
  }

  const int r4 = (lane >> 4) * 4;
#pragma unroll
  for (int mi = 0; mi < 4; mi++){
#pragma unroll
    for (int ni = 0; ni < 4; ni++){
      const int col = n0 + wn*64 + ni*16 + fr;
      const float bb = BIAS ? bias[col] : 0.f;
#pragma unroll
      for (int r = 0; r < 4; r++){
        const int row = m0 + wm*64 + mi*16 + r4 + r;
        float v = acc[mi][ni][r] + bb;
        if (EPI == 0){
          u16 hv = f2bf(v), lv = f2bf(v - bf2f(hv));
          long idx = coff + (long)row*ldc + col;
          ((u16*)Cv)[idx] = hv;
          ((u16*)Cv)[idx + loOffC] = lv;
        } else if (EPI == 1){
          ((float*)Cv)[coff + (long)row*ldc + col] = v;
        } else if (EPI == 2){
          long idx = coff + (long)row*ldc + col;
          ((float*)Cv)[idx] = v + Res[idx];
        } else {                      // EPI==3: V transpose, packed hi|lo
          u16 hv = f2bf(v), lv = f2bf(v - bf2f(hv));
          int b = row >> 10, q = row & 1023;
          int h = col >> 8, d = col & 255;
          long o = ((long)(b*NHc + h)*HDc + d)*2048 + q;
          ((u16*)Cv)[o] = hv;
          ((u16*)Cv)[o + 1024] = lv;
        }
      }
    }
  }
}

// ---------------------------------------------------------------------------
// Plain bf16 NT GEMM (m97 structure), linear-z batched.
// EPI: 0 = store bf16, 1 = store f32, 2 = f32 +=
template<int EPI>
__global__ __launch_bounds__(256)
void gemm_bt(const u16* __restrict__ A, const u16* __restrict__ B,
             void* __restrict__ Cv,
             int M, int N, int K, int lda, int ldb, int ldc,
             long sAz, long sBz, long sCz)
{
  __shared__ u16 lsA[128*32];
  __shared__ u16 lsB[128*32];
  const int z = blockIdx.z;
  const u16* Ab = A + (long)z*sAz;
  const u16* Bb = B + (long)z*sBz;
  const int n0 = blockIdx.x*128, m0 = blockIdx.y*128;
  const int t = threadIdx.x, lane = t & 63;
  const int w = t >> 6, wm = w >> 1, wn = w & 1;
  const int fr = lane & 15, kg = lane >> 4;
  const int srow = t >> 2, scol = (t & 3) * 8;
  f32x4 acc[4][4] = {};

  for (int kb = 0; kb < K; kb += 32){
    gload_lds16(Ab + (long)(m0 +      srow)*lda + kb + scol, &lsA[srow*32 + scol]);
    gload_lds16(Ab + (long)(m0 + 64 + srow)*lda + kb + scol, &lsA[(64+srow)*32 + scol]);
    gload_lds16(Bb + (long)(n0 +      srow)*ldb + kb + scol, &lsB[srow*32 + scol]);
    gload_lds16(Bb + (long)(n0 + 64 + srow)*ldb + kb + scol, &lsB[(64+srow)*32 + scol]);
    asm volatile("s_waitcnt vmcnt(0)" ::: "memory");
    __syncthreads();
    bf16x8 av[4], bv[4];
#pragma unroll
    for (int i = 0; i < 4; i++){
      av[i] = *(const bf16x8*)&lsA[(wm*64 + i*16 + fr)*32 + kg*8];
      bv[i] = *(const bf16x8*)&lsB[(wn*64 + i*16 + fr)*32 + kg*8];
    }
#pragma unroll
    for (int mi = 0; mi < 4; mi++)
#pragma unroll
      for (int ni = 0; ni < 4; ni++)
        acc[mi][ni] = __builtin_amdgcn_mfma_f32_16x16x32_bf16(av[mi], bv[ni], acc[mi][ni], 0, 0, 0);
    __syncthreads();
  }

  const int r4 = (lane >> 4) * 4;
#pragma unroll
  for (int mi = 0; mi < 4; mi++){
#pragma unroll
    for (int ni = 0; ni < 4; ni++){
      const int col = n0 + wn*64 + ni*16 + fr;
#pragma unroll
      for (int r = 0; r < 4; r++){
        const int row = m0 + wm*64 + mi*16 + r4 + r;
        const long idx = (long)z*sCz + (long)row*ldc + col;
        float v = acc[mi][ni][r];
        if      (EPI == 0) ((u16*)Cv)[idx]   = f2bf(v);
        else if (EPI == 1) ((float*)Cv)[idx] = v;
        else               ((float*)Cv)[idx] += v;
      }
    }
  }
}

// ---------------------------------------------------------------------------
__global__ void cast_bf16_k(const float* __restrict__ in, u16* __restrict__ out, long n){
  long i = (long)blockIdx.x*blockDim.x + threadIdx.x;
  long st = (long)gridDim.x*blockDim.x;
  for (; i < n; i += st) out[i] = f2bf(in[i]);
}

__global__ void split_cast_k(const float* __restrict__ in, u16* __restrict__ hi,
                             u16* __restrict__ lo, long n){
  long i = (long)blockIdx.x*blockDim.x + threadIdx.x;
  long st = (long)gridDim.x*blockDim.x;
  for (; i < n; i += st){
    float v = in[i];
    u16 h = f2bf(v);
    hi[i] = h;
    lo[i] = f2bf(v - bf2f(h));
  }
}

// routed gate/up folded with expert_norm_w: wgu[e][i][h]=g*nw, wgu[e][256+i][h]=u*nw
__global__ void fold_expert_k(const float* __restrict__ g, const float* __restrict__ u,
                              const float* __restrict__ nw, u16* __restrict__ gu, long n){
  long i = (long)blockIdx.x*blockDim.x + threadIdx.x;
  long st = (long)gridDim.x*blockDim.x;
  for (; i < n; i += st){
    int h  = (int)(i & (Hc - 1));
    int ii = (int)((i >> 10) & (Ic - 1));
    int e  = (int)(i >> 18);
    float wv = nw[e*Hc + h];
    long o = (long)e*(2*Ic*Hc) + (long)ii*Hc + h;
    gu[o]         = f2bf(g[i]*wv);
    gu[o + Ic*Hc] = f2bf(u[i]*wv);
  }
}

// down-proj transposed fold: out[h][e*256+k] = Wed[e][h][k]
__global__ void fold_down_k(const float* __restrict__ wd, u16* __restrict__ out, long n){
  long i = (long)blockIdx.x*blockDim.x + threadIdx.x;
  long st = (long)gridDim.x*blockDim.x;
  for (; i < n; i += st){
    int k = (int)(i & (Ic - 1));
    int h = (int)((i >> 8) & (Hc - 1));
    int e = (int)(i >> 18);
    out[(long)h*2048 + e*Ic + k] = f2bf(wd[i]);
  }
}

// rmsnorm -> packed hi|lo u16 rows [row][2048]
__global__ __launch_bounds__(256)
void rmsnorm_split_k(const float* __restrict__ x, const float* __restrict__ w1,
                     u16* __restrict__ o){
  const int row = blockIdx.x, t = threadIdx.x, lane = t & 63, w = t >> 6;
  float4 v = ((const float4*)(x + (long)row*Hc))[t];
  float ss = v.x*v.x + v.y*v.y + v.z*v.z + v.w*v.w;
  for (int off = 32; off; off >>= 1) ss += __shfl_xor(ss, off);
  __shared__ float red[4];
  if (lane == 0) red[w] = ss;
  __syncthreads();
  float rs = rsqrtf((red[0]+red[1]+red[2]+red[3])*(1.f/Hc) + EPSc);
  float4 wv = ((const float4*)w1)[t];
  float f0 = v.x*rs*wv.x, f1 = v.y*rs*wv.y, f2 = v.z*rs*wv.z, f3 = v.w*rs*wv.w;
  ushort4 hv, lv;
  hv.x = f2bf(f0); lv.x = f2bf(f0 - bf2f(hv.x));
  hv.y = f2bf(f1); lv.y = f2bf(f1 - bf2f(hv.y));
  hv.z = f2bf(f2); lv.z = f2bf(f2 - bf2f(hv.z));
  hv.w = f2bf(f3); lv.w = f2bf(f3 - bf2f(hv.w));
  u16* r16 = o + (long)row*2048;
  ((ushort4*)r16)[t] = hv;
  ((ushort4*)(r16 + 1024))[t] = lv;
}

// rmsnorm -> two plain bf16 outputs (xhat with w=1, sx with shared_norm_w)
__global__ __launch_bounds__(256)
void rmsnorm_k(const float* __restrict__ x, u16* __restrict__ o1,
               const float* __restrict__ w2, u16* __restrict__ o2){
  const int row = blockIdx.x, t = threadIdx.x, lane = t & 63, w = t >> 6;
  float4 v = ((const float4*)(x + (long)row*Hc))[t];
  float ss = v.x*v.x + v.y*v.y + v.z*v.z + v.w*v.w;
  for (int off = 32; off; off >>= 1) ss += __shfl_xor(ss, off);
  __shared__ float red[4];
  if (lane == 0) red[w] = ss;
  __syncthreads();
  float rs = rsqrtf((red[0]+red[1]+red[2]+red[3])*(1.f/Hc) + EPSc);
  ushort4 ov;
  ov.x = f2bf(v.x*rs); ov.y = f2bf(v.y*rs); ov.z = f2bf(v.z*rs); ov.w = f2bf(v.w*rs);
  ((ushort4*)o1)[(long)row*256 + t] = ov;
  float4 wv = ((const float4*)w2)[t];
  ov.x = f2bf(v.x*rs*wv.x); ov.y = f2bf(v.y*rs*wv.y);
  ov.z = f2bf(v.z*rs*wv.z); ov.w = f2bf(v.w*rs*wv.w);
  ((ushort4*)o2)[(long)row*256 + t] = ov;
}

// masked softmax over f32 S rows; writes packed hi|lo P in place.
// rid = slice*1024 + q; batch = bbase + (slice&3)
__global__ __launch_bounds__(256)
void softmax2_k(float* __restrict__ S, const int* __restrict__ cnt, int bbase){
  const int rid = blockIdx.x;
  const int b = bbase + ((rid >> 10) & 3);
  float* row = S + (long)rid*Lc;
  const int n = cnt[b];
  const int t = threadIdx.x, lane = t & 63, w = t >> 6;
  float4 v = ((const float4*)row)[t];
  const float sc = 0.0625f;
  float vals[4] = {v.x*sc, v.y*sc, v.z*sc, v.w*sc};
  const int c = t*4;
  float m = -3.4e38f;
#pragma unroll
  for (int j = 0; j < 4; j++) if (c + j < n) m = fmaxf(m, vals[j]);
  for (int o = 32; o; o >>= 1) m = fmaxf(m, __shfl_xor(m, o));
  __shared__ float red[8];
  if (lane == 0) red[w] = m;
  __syncthreads();
  m = fmaxf(fmaxf(red[0], red[1]), fmaxf(red[2], red[3]));
  float p[4], s = 0.f;
#pragma unroll
  for (int j = 0; j < 4; j++){ p[j] = (c + j < n) ? __expf(vals[j] - m) : 0.f; s += p[j]; }
  for (int o = 32; o; o >>= 1) s += __shfl_xor(s, o);
  if (lane == 0) red[4 + w] = s;
  __syncthreads();
  const float inv = 1.f / (red[4]+red[5]+red[6]+red[7]);
  ushort4 hv, lv;
  float q0 = p[0]*inv, q1 = p[1]*inv, q2 = p[2]*inv, q3 = p[3]*inv;
  hv.x = f2bf(q0); lv.x = f2bf(q0 - bf2f(hv.x));
  hv.y = f2bf(q1); lv.y = f2bf(q1 - bf2f(hv.y));
  hv.z = f2bf(q2); lv.z = f2bf(q2 - bf2f(hv.z));
  hv.w = f2bf(q3); lv.w = f2bf(q3 - bf2f(hv.w));
  u16* r16 = (u16*)S + (long)rid*2048;
  ((ushort4*)r16)[t] = hv;
  ((ushort4*)(r16 + 1024))[t] = lv;
}

// gating: one wave per token, f32
__global__ __launch_bounds__(256)
void gating_k(const float* __restrict__ x, const float* __restrict__ gnw,
              const float* __restrict__ gw, int* __restrict__ topi, float* __restrict__ topw){
  const int t = threadIdx.x, lane = t & 63, w = t >> 6;
  const int n = blockIdx.x*4 + w;
  const float* xr = x + (long)n*Hc;
  float ss = 0.f, sc[8] = {0,0,0,0,0,0,0,0};
  for (int j = 0; j < 16; j++){
    int d = j*64 + lane;
    float xv = xr[d];
    ss += xv*xv;
    float xg = xv * gnw[d];
#pragma unroll
    for (int e = 0; e < 8; e++) sc[e] += xg * gw[e*Hc + d];
  }
  for (int o = 32; o; o >>= 1){
    ss += __shfl_xor(ss, o);
#pragma unroll
    for (int e = 0; e < 8; e++) sc[e] += __shfl_xor(sc[e], o);
  }
  float rs = rsqrtf(ss*(1.f/Hc) + EPSc);
  float m = -3.4e38f;
#pragma unroll
  for (int e = 0; e < 8; e++){ sc[e] *= rs; m = fmaxf(m, sc[e]); }
  float p[8], sum = 0.f;
#pragma unroll
  for (int e = 0; e < 8; e++){ p[e] = __expf(sc[e] - m); sum += p[e]; }
  float inv = 1.f/sum;
#pragma unroll
  for (int e = 0; e < 8; e++) p[e] *= inv;
  int i1 = 0; float v1 = p[0];
#pragma unroll
  for (int e = 1; e < 8; e++) if (p[e] > v1){ v1 = p[e]; i1 = e; }
  int i2 = -1; float v2 = -1.f;
#pragma unroll
  for (int e = 0; e < 8; e++) if (e != i1 && p[e] > v2){ v2 = p[e]; i2 = e; }
  if (lane == 0){
    float dn = v1 + v2 + 1e-20f;
    topi[2*n] = i1; topi[2*n + 1] = i2;
    topw[2*n] = v1/dn; topw[2*n + 1] = v2/dn;
  }
}

__global__ void act_shared_k(const u16* __restrict__ gu, u16* __restrict__ z, long n){
  long i = (long)blockIdx.x*blockDim.x + threadIdx.x;
  long st = (long)gridDim.x*blockDim.x;
  for (; i < n; i += st){
    long nn = i >> 9;
    int  ii = (int)(i & (ISc - 1));
    float gv = bf2f(gu[nn*1024 + ii]);
    float uv = bf2f(gu[nn*1024 + ISc + ii]);
    z[i] = f2bf(gv/(1.f + __expf(-gv)) * uv);
  }
}

// all-expert act: gu=[tok][e*512+{g:0..255,u:256..511}] -> z[tok][e*256+i]
__global__ void act_expert_all_k(const u16* __restrict__ gu, const int* __restrict__ topi,
                                 const float* __restrict__ topw, u16* __restrict__ z, long n){
  long i = (long)blockIdx.x*blockDim.x + threadIdx.x;
  long st = (long)gridDim.x*blockDim.x;
  for (; i < n; i += st){
    long nn = i >> 11;
    int rem = (int)(i & 2047);
    int e = rem >> 8, ii = rem & 255;
    float wv = 0.f;
    if      (topi[2*nn]     == e) wv = topw[2*nn];
    else if (topi[2*nn + 1] == e) wv = topw[2*nn + 1];
    float gv = bf2f(gu[nn*4096 + e*512 + ii]);
    float uv = bf2f(gu[nn*4096 + e*512 + 256 + ii]);
    z[i] = f2bf(gv/(1.f + __expf(-gv)) * uv * wv);
  }
}

// per-expert act (fallback path)
__global__ void act_expert_k(const u16* __restrict__ gu, const int* __restrict__ topi,
                             const float* __restrict__ topw, int e,
                             u16* __restrict__ z, long n){
  long i = (long)blockIdx.x*blockDim.x + threadIdx.x;
  long st = (long)gridDim.x*blockDim.x;
  for (; i < n; i += st){
    long nn = i >> 8;
    int  ii = (int)(i & (Ic - 1));
    float wv = 0.f;
    if      (topi[2*nn]     == e) wv = topw[2*nn];
    else if (topi[2*nn + 1] == e) wv = topw[2*nn + 1];
    float gv = bf2f(gu[nn*512 + ii]);
    float uv = bf2f(gu[nn*512 + Ic + ii]);
    z[i] = f2bf(gv/(1.f + __expf(-gv)) * uv * wv);
  }
}

__global__ __launch_bounds__(256)
void final_k(const float* __restrict__ y, const float* __restrict__ ogw,
             const float* __restrict__ ogb, const int* __restrict__ cnt,
             float* __restrict__ out){
  const int t = threadIdx.x, lane = t & 63, w = t >> 6;
  const int n = blockIdx.x*4 + w;
  const int b = n >> 10, l = n & 1023;
  const bool pad = l >= cnt[b];
  const float* yr = y + (long)n*Hc;
  float dot = 0.f, yv[16];
#pragma unroll
  for (int j = 0; j < 16; j++){
    int d = j*64 + lane;
    yv[j] = yr[d];
    dot += yv[j]*ogw[d];
  }
  for (int o = 32; o; o >>= 1) dot += __shfl_xor(dot, o);
  float s = 1.f/(1.f + __expf(-(dot + ogb[0])));
  float* outr = out + (long)n*Hc;
#pragma unroll
  for (int j = 0; j < 16; j++){
    int d = j*64 + lane;
    outr[d] = pad ? 0.f : yv[j]*s;
  }
}

__global__ void sentinel_k(float* out){ out[0] = 1.0e9f; }

// ---------------------------------------------------------------------------
extern "C" void kernel_launch(void* const* d_in, const int* in_sizes, int n_in,
                              void* d_out, int out_size, void* d_ws, size_t ws_size,
                              hipStream_t stream){
  const float* hidden  = (const float*)d_in[0];
  const int*   cnt     = (const int*)  d_in[1];
  const float* ctx_nw  = (const float*)d_in[2];
  const float* Wqkv    = (const float*)d_in[3];
  const float* in_b    = (const float*)d_in[4];
  const float* Woutp   = (const float*)d_in[5];
  const float* out_b   = (const float*)d_in[6];
  const float* gate_nw = (const float*)d_in[7];
  const float* gate_w  = (const float*)d_in[8];
  const float* exp_nw  = (const float*)d_in[9];
  const float* Weg     = (const float*)d_in[10];
  const float* Weu     = (const float*)d_in[11];
  const float* Wed     = (const float*)d_in[12];
  const float* sh_nw   = (const float*)d_in[13];
  const float* Wsg     = (const float*)d_in[14];
  const float* Wsu     = (const float*)d_in[15];
  const float* Wsd     = (const float*)d_in[16];
  const float* ogw     = (const float*)d_in[17];
  const float* ogb     = (const float*)d_in[18];
  float* out = (float*)d_out;

  const size_t MB = 1024*1024;
  char* ws = (char*)d_ws;
  size_t off = 0;
  auto alloc = [&](size_t bytes)->char*{
    char* p = ws + off; off += (bytes + 255) & ~(size_t)255; return p;
  };
  // weights
  u16* wWqH  = (u16*)alloc((size_t)3072*1024*2);
  u16* wWqL  = (u16*)alloc((size_t)3072*1024*2);
  u16* wWoH  = (u16*)alloc((size_t)1024*1024*2);
  u16* wWoL  = (u16*)alloc((size_t)1024*1024*2);
  u16* wWgu  = (u16*)alloc((size_t)Ec*2*Ic*Hc*2);
  u16* wWdU  = (u16*)alloc((size_t)Ec*Hc*Ic*2);    // big: [H][E*I] transposed; small: [E][H][I]
  u16* wWsgu = (u16*)alloc((size_t)2*ISc*Hc*2);
  u16* wWsd  = (u16*)alloc((size_t)Hc*ISc*2);
  int*   wTopI = (int*)  alloc((size_t)NTOK*2*4);
  float* wTopW = (float*)alloc((size_t)NTOK*2*4);
  // arenas
  char* P1 = alloc(32*MB);   // nx packed -> ctx packed -> Y f32
  char* P2 = alloc(32*MB);   // Qp packed -> Xhat bf16 + Sx bf16
  char* P3 = alloc(32*MB);   // Kp packed -> X f32 -> Z_all (big) / expGU+Ze (small)
  char* P4 = alloc(32*MB);   // Vtp packed -> shGU + Zs
  size_t fixed = off;
  const bool big = (fixed + 64*MB) <= ws_size;
  char* P5 = alloc(big ? 64*MB : 16*MB);  // S f32 -> GU_all (big)
  if (off > ws_size){ sentinel_k<<<1,1,0,stream>>>(out); return; }

  u16*   wNx   = (u16*)P1;
  u16*   wCtx  = (u16*)P1;
  float* wY    = (float*)P1;
  u16*   wQp   = (u16*)P2;
  u16*   wXhat = (u16*)P2;
  u16*   wSx   = (u16*)(P2 + 16*MB);
  u16*   wKp   = (u16*)P3;
  float* wX    = (float*)P3;
  u16*   wZall = (u16*)P3;               // big: [8192][2048]
  u16*   wGUe  = (u16*)P3;               // small
  u16*   wZe   = (u16*)(P3 + 8*MB);      // small
  u16*   wVtp  = (u16*)P4;
  u16*   wGUs  = (u16*)P4;
  u16*   wZs   = (u16*)(P4 + 16*MB);
  float* wS    = (float*)P5;
  u16*   wGUall= (u16*)P5;               // big: [8192][4096]

  // 1) weight prep
  split_cast_k<<<4096, 256, 0, stream>>>(Wqkv,  wWqH, wWqL, (long)3072*1024);
  split_cast_k<<<2048, 256, 0, stream>>>(Woutp, wWoH, wWoL, (long)1024*1024);
  if (big) fold_down_k<<<2048, 256, 0, stream>>>(Wed, wWdU, (long)Ec*Hc*Ic);
  else     cast_bf16_k<<<2048, 256, 0, stream>>>(Wed, wWdU, (long)Ec*Hc*Ic);
  cast_bf16_k<<<1024, 256, 0, stream>>>(Wsg, wWsgu,                (long)ISc*Hc);
  cast_bf16_k<<<1024, 256, 0, stream>>>(Wsu, wWsgu + (long)ISc*Hc, (long)ISc*Hc);
  cast_bf16_k<<<1024, 256, 0, stream>>>(Wsd, wWsd, (long)Hc*ISc);
  fold_expert_k<<<2048, 256, 0, stream>>>(Weg, Weu, exp_nw, wWgu, (long)Ec*Ic*Hc);

  // 2) pre-attn norm (split) + Q/K/V projections (split precision)
  rmsnorm_split_k<<<NTOK, 256, 0, stream>>>(hidden, ctx_nw, wNx);
  gemm3<0, true><<<dim3(8, 64, 1), 256, 0, stream>>>(
      wNx, wNx + 1024, wWqH, wWqL, wQp, in_b, nullptr,
      NTOK, 1024, 1024, 2048, 1024, 2048, 0,0,0,0,0,0, 1024);
  gemm3<0, true><<<dim3(8, 64, 1), 256, 0, stream>>>(
      wNx, wNx + 1024, wWqH + (long)1024*1024, wWqL + (long)1024*1024, wKp,
      in_b + 1024, nullptr, NTOK, 1024, 1024, 2048, 1024, 2048, 0,0,0,0,0,0, 1024);
  gemm3<3, true><<<dim3(8, 64, 1), 256, 0, stream>>>(
      wNx, wNx + 1024, wWqH + (long)2048*1024, wWqL + (long)2048*1024, wVtp,
      in_b + 2048, nullptr, NTOK, 1024, 1024, 2048, 1024, 0, 0,0,0,0,0,0, 0);

  // 3) attention, zper slices per launch: z = (head<<2) | batch_in_half
  const int zper = big ? 16 : 4;
  const int ngroups = 32 / zper;
  for (int g = 0; g < ngroups; g++){
    const int hf    = big ? g : (g >> 2);
    const int hbase = big ? 0 : (g & 3);
    const long tokoff = (long)hf*4*Lc*2048;
    const u16* Qb = wQp + tokoff + hbase*HDc;
    const u16* Kb = wKp + tokoff + hbase*HDc;
    // QK^T -> S f32
    gemm3<1, false><<<dim3(8, 8, zper), 256, 0, stream>>>(
        Qb, Qb + 1024, Kb, Kb + 1024, wS, nullptr, nullptr,
        Lc, Lc, HDc, 2048, 2048, Lc,
        (long)Lc*2048, (long)HDc,          // A: batch, head
        (long)Lc*2048, (long)HDc,          // B: batch, head
        (long)Lc*Lc,   (long)4*Lc*Lc, 0);  // C: slice linear
    softmax2_k<<<zper*1024, 256, 0, stream>>>(wS, cnt, hf*4);
    // PV -> ctx packed hi|lo
    const u16* Vb = wVtp + (long)hf*4*NHc*HDc*2048 + (long)hbase*HDc*2048;
    u16* Cb = wCtx + tokoff + hbase*HDc;
    gemm3<0, false><<<dim3(2, 8, zper), 256, 0, stream>>>(
        (const u16*)wS, (const u16*)wS + 1024, Vb, Vb + 1024, Cb, nullptr, nullptr,
        Lc, HDc, Lc, 2048, 2048, 2048,
        (long)Lc*2048,     (long)4*Lc*2048,     // A (P): batch, head (slice linear)
        (long)NHc*HDc*2048,(long)HDc*2048,      // B (Vt): batch, head
        (long)Lc*2048,     (long)HDc, 1024);    // C (ctx): batch, head
  }

  // 4) out-proj + bias + residual -> X f32
  gemm3<2, true><<<dim3(8, 64, 1), 256, 0, stream>>>(
      wCtx, wCtx + 1024, wWoH, wWoL, wX, out_b, hidden,
      NTOK, 1024, 1024, 2048, 1024, 1024, 0,0,0,0,0,0, 0);

  // 5) gating + post-norms
  gating_k<<<NTOK/4, 256, 0, stream>>>(wX, gate_nw, gate_w, wTopI, wTopW);
  rmsnorm_k<<<NTOK, 256, 0, stream>>>(wX, wXhat, sh_nw, wSx);

  // 6) shared experts -> Y
  gemm_bt<0><<<dim3(8, 64, 1), 256, 0, stream>>>(
      wSx, wWsgu, wGUs, NTOK, 2*ISc, 1024, 1024, 1024, 2*ISc, 0, 0, 0);
  act_shared_k<<<4096, 256, 0, stream>>>(wGUs, wZs, (long)NTOK*ISc);
  gemm_bt<1><<<dim3(8, 64, 1), 256, 0, stream>>>(
      wZs, wWsd, wY, NTOK, 1024, ISc, ISc, ISc, 1024, 0, 0, 0);

  // 7) routed experts
  if (big){
    // one z=8 gate/up GEMM: GU_all[tok][e*512 + col]
    gemm_bt<0><<<dim3(4, 64, Ec), 256, 0, stream>>>(
        wXhat, wWgu, wGUall, NTOK, 2*Ic, 1024, 1024, 1024, 4096,
        0, (long)2*Ic*Hc, (long)2*Ic);
    act_expert_all_k<<<4096, 256, 0, stream>>>(
        wGUall, wTopI, wTopW, wZall, (long)NTOK*Ec*Ic);
    // one down GEMM over K = E*I = 2048 with transposed-folded weights
    gemm_bt<2><<<dim3(8, 64, 1), 256, 0, stream>>>(
        wZall, wWdU, wY, NTOK, 1024, 2048, 2048, 2048, 1024, 0, 0, 0);
  } else {
    for (int e = 0; e < Ec; e++){
      gemm_bt<0><<<dim3(4, 64, 1), 256, 0, stream>>>(
          wXhat, wWgu + (long)e*2*Ic*Hc, wGUe, NTOK, 2*Ic, 1024, 1024, 1024, 2*Ic, 0,0,0);
      act_expert_k<<<2048, 256, 0, stream>>>(wGUe, wTopI, wTopW, e, wZe, (long)NTOK*Ic);
      gemm_bt<2><<<dim3(8, 64, 1), 256, 0, stream>>>(
          wZe, wWdU + (long)e*Hc*Ic, wY, NTOK, 1024, Ic, Ic, Ic, 1024, 0,0,0);
    }
  }

  // 8) out gate + padding mask
  final_k<<<NTOK/4, 256, 0, stream>>>(wY, ogw, ogb, cnt, out);
}

// Round 6
// 789.203 us; speedup vs baseline: 1.7806x; 1.0663x over previous
//
#include <hip/hip_runtime.h>
#include <hip/hip_bf16.h>

typedef unsigned short u16;
typedef unsigned int   u32;
typedef short bf16x8 __attribute__((ext_vector_type(8)));
typedef float f32x4  __attribute__((ext_vector_type(4)));

#define DEV static __device__ __forceinline__

#define Bc 8
#define Lc 1024
#define Hc 1024
#define Ec 8
#define Ic 256
#define ISc 512
#define NHc 4
#define HDc 256
#define NTOK 8192
#define EPSc 1e-6f
#define MAXSLOTS 17408   // 2*8192 + 8*128 pad headroom, /128 = 136

DEV u16 f2bf(float f){
  u32 u = __float_as_uint(f);
  return (u16)((u + 0x7fffu + ((u >> 16) & 1u)) >> 16);
}
DEV float bf2f(u16 h){ return __uint_as_float(((u32)h) << 16); }

DEV void gload_lds16(const void* g, void* l){
  __builtin_amdgcn_global_load_lds((const __attribute__((address_space(1))) u32*)g,
                                   (__attribute__((address_space(3))) u32*)l, 16, 0, 0);
}

// ---------------------------------------------------------------------------
// Split-precision NT GEMM: C = (Ahi+Alo)·(Bhi+Blo)^T ≈ AhiBhi + AhiBlo + AloBhi
// z decomposes as zin = z&3, zout = z>>2.
// EPI: 0 = packed hi|lo u16 store (lo at +loOffC), 1 = f32 store,
//      2 = f32 = acc + bias + Res, 3 = V-transpose packed hi|lo
// SKIP: 0 none; 1 = exit if n0 >= tc[bbase+zin]; 2 = clamp K to ceil(tc/32)*32
// ---------------------------------------------------------------------------
template<int EPI, int BIAS, int SKIP>
__global__ __launch_bounds__(256)
void gemm3(const u16* __restrict__ Ahi, const u16* __restrict__ Alo,
           const u16* __restrict__ Bhi, const u16* __restrict__ Blo,
           void* __restrict__ Cv, const float* __restrict__ bias,
           const float* __restrict__ Res,
           int M, int N, int K, int lda, int ldb, int ldc,
           long sAin, long sAout, long sBin, long sBout, long sCin, long sCout,
           int loOffC, int biasStride, const int* __restrict__ tc, int bbase)
{
  __shared__ u16 lsAh[128*32];
  __shared__ u16 lsAl[128*32];
  __shared__ u16 lsBh[128*32];
  __shared__ u16 lsBl[128*32];
  const int z = blockIdx.z, zin = z & 3, zout = z >> 2;
  const int n0 = blockIdx.x*128, m0 = blockIdx.y*128;
  if (SKIP == 1){ if (n0 >= tc[bbase + zin]) return; }
  if (SKIP == 2){ int kl = (tc[bbase + zin] + 31) & ~31; K = K < kl ? K : kl; }
  const long aoff = (long)zin*sAin + (long)zout*sAout;
  const long boff = (long)zin*sBin + (long)zout*sBout;
  const long coff = (long)zin*sCin + (long)zout*sCout;
  const u16* Ahb = Ahi + aoff;
  const u16* Alb = Alo + aoff;
  const u16* Bhb = Bhi + boff;
  const u16* Blb = Blo + boff;
  const int t = threadIdx.x, lane = t & 63;
  const int w = t >> 6, wm = w >> 1, wn = w & 1;
  const int fr = lane & 15, kg = lane >> 4;
  const int srow = t >> 2, scol = (t & 3) * 8;
  f32x4 acc[4][4] = {};

  for (int kb = 0; kb < K; kb += 32){
    gload_lds16(Ahb + (long)(m0 +      srow)*lda + kb + scol, &lsAh[srow*32 + scol]);
    gload_lds16(Ahb + (long)(m0 + 64 + srow)*lda + kb + scol, &lsAh[(64+srow)*32 + scol]);
    gload_lds16(Alb + (long)(m0 +      srow)*lda + kb + scol, &lsAl[srow*32 + scol]);
    gload_lds16(Alb + (long)(m0 + 64 + srow)*lda + kb + scol, &lsAl[(64+srow)*32 + scol]);
    gload_lds16(Bhb + (long)(n0 +      srow)*ldb + kb + scol, &lsBh[srow*32 + scol]);
    gload_lds16(Bhb + (long)(n0 + 64 + srow)*ldb + kb + scol, &lsBh[(64+srow)*32 + scol]);
    gload_lds16(Blb + (long)(n0 +      srow)*ldb + kb + scol, &lsBl[srow*32 + scol]);
    gload_lds16(Blb + (long)(n0 + 64 + srow)*ldb + kb + scol, &lsBl[(64+srow)*32 + scol]);
    asm volatile("s_waitcnt vmcnt(0)" ::: "memory");
    __syncthreads();
    bf16x8 ah[4], al[4], bh[4], bl[4];
#pragma unroll
    for (int i = 0; i < 4; i++){
      ah[i] = *(const bf16x8*)&lsAh[(wm*64 + i*16 + fr)*32 + kg*8];
      al[i] = *(const bf16x8*)&lsAl[(wm*64 + i*16 + fr)*32 + kg*8];
      bh[i] = *(const bf16x8*)&lsBh[(wn*64 + i*16 + fr)*32 + kg*8];
      bl[i] = *(const bf16x8*)&lsBl[(wn*64 + i*16 + fr)*32 + kg*8];
    }
#pragma unroll
    for (int mi = 0; mi < 4; mi++)
#pragma unroll
      for (int ni = 0; ni < 4; ni++){
        acc[mi][ni] = __builtin_amdgcn_mfma_f32_16x16x32_bf16(ah[mi], bh[ni], acc[mi][ni], 0, 0, 0);
        acc[mi][ni] = __builtin_amdgcn_mfma_f32_16x16x32_bf16(ah[mi], bl[ni], acc[mi][ni], 0, 0, 0);
        acc[mi][ni] = __builtin_amdgcn_mfma_f32_16x16x32_bf16(al[mi], bh[ni], acc[mi][ni], 0, 0, 0);
      }
    __syncthreads();
  }

  const int r4 = (lane >> 4) * 4;
#pragma unroll
  for (int mi = 0; mi < 4; mi++){
#pragma unroll
    for (int ni = 0; ni < 4; ni++){
      const int col = n0 + wn*64 + ni*16 + fr;
      const float bb = BIAS ? bias[zin*biasStride + col] : 0.f;
#pragma unroll
      for (int r = 0; r < 4; r++){
        const int row = m0 + wm*64 + mi*16 + r4 + r;
        float v = acc[mi][ni][r] + bb;
        if (EPI == 0){
          u16 hv = f2bf(v), lv = f2bf(v - bf2f(hv));
          long idx = coff + (long)row*ldc + col;
          ((u16*)Cv)[idx] = hv;
          ((u16*)Cv)[idx + loOffC] = lv;
        } else if (EPI == 1){
          ((float*)Cv)[coff + (long)row*ldc + col] = v;
        } else if (EPI == 2){
          long idx = coff + (long)row*ldc + col;
          ((float*)Cv)[idx] = v + Res[idx];
        } else {                      // EPI==3: V transpose, packed hi|lo
          u16 hv = f2bf(v), lv = f2bf(v - bf2f(hv));
          int b = row >> 10, q = row & 1023;
          int h = col >> 8, d = col & 255;
          long o = ((long)(b*NHc + h)*HDc + d)*2048 + q;
          ((u16*)Cv)[o] = hv;
          ((u16*)Cv)[o + 1024] = lv;
        }
      }
    }
  }
}

// ---------------------------------------------------------------------------
// Plain bf16 NT GEMM, linear-z batched. EPI: 0 bf16, 1 f32, 2 f32 +=
template<int EPI>
__global__ __launch_bounds__(256)
void gemm_bt(const u16* __restrict__ A, const u16* __restrict__ B,
             void* __restrict__ Cv,
             int M, int N, int K, int lda, int ldb, int ldc,
             long sAz, long sBz, long sCz)
{
  __shared__ u16 lsA[128*32];
  __shared__ u16 lsB[128*32];
  const int z = blockIdx.z;
  const u16* Ab = A + (long)z*sAz;
  const u16* Bb = B + (long)z*sBz;
  const int n0 = blockIdx.x*128, m0 = blockIdx.y*128;
  const int t = threadIdx.x, lane = t & 63;
  const int w = t >> 6, wm = w >> 1, wn = w & 1;
  const int fr = lane & 15, kg = lane >> 4;
  const int srow = t >> 2, scol = (t & 3) * 8;
  f32x4 acc[4][4] = {};

  for (int kb = 0; kb < K; kb += 32){
    gload_lds16(Ab + (long)(m0 +      srow)*lda + kb + scol, &lsA[srow*32 + scol]);
    gload_lds16(Ab + (long)(m0 + 64 + srow)*lda + kb + scol, &lsA[(64+srow)*32 + scol]);
    gload_lds16(Bb + (long)(n0 +      srow)*ldb + kb + scol, &lsB[srow*32 + scol]);
    gload_lds16(Bb + (long)(n0 + 64 + srow)*ldb + kb + scol, &lsB[(64+srow)*32 + scol]);
    asm volatile("s_waitcnt vmcnt(0)" ::: "memory");
    __syncthreads();
    bf16x8 av[4], bv[4];
#pragma unroll
    for (int i = 0; i < 4; i++){
      av[i] = *(const bf16x8*)&lsA[(wm*64 + i*16 + fr)*32 + kg*8];
      bv[i] = *(const bf16x8*)&lsB[(wn*64 + i*16 + fr)*32 + kg*8];
    }
#pragma unroll
    for (int mi = 0; mi < 4; mi++)
#pragma unroll
      for (int ni = 0; ni < 4; ni++)
        acc[mi][ni] = __builtin_amdgcn_mfma_f32_16x16x32_bf16(av[mi], bv[ni], acc[mi][ni], 0, 0, 0);
    __syncthreads();
  }

  const int r4 = (lane >> 4) * 4;
#pragma unroll
  for (int mi = 0; mi < 4; mi++){
#pragma unroll
    for (int ni = 0; ni < 4; ni++){
      const int col = n0 + wn*64 + ni*16 + fr;
#pragma unroll
      for (int r = 0; r < 4; r++){
        const int row = m0 + wm*64 + mi*16 + r4 + r;
        const long idx = (long)z*sCz + (long)row*ldc + col;
        float v = acc[mi][ni][r];
        if      (EPI == 0) ((u16*)Cv)[idx]   = f2bf(v);
        else if (EPI == 1) ((float*)Cv)[idx] = v;
        else               ((float*)Cv)[idx] += v;
      }
    }
  }
}

// ---------------------------------------------------------------------------
// Gathered GU GEMM: per expert e, rows = tokens from sidx; C -> GUg[offs[e]+slot][512]
__global__ __launch_bounds__(256)
void gemm_gu_gather(const u16* __restrict__ A, const u16* __restrict__ Ball,
                    u16* __restrict__ Cg, const int* __restrict__ sidx,
                    const int* __restrict__ counts, const int* __restrict__ offs)
{
  __shared__ u16 lsA[128*32];
  __shared__ u16 lsB[128*32];
  const int e = blockIdx.z;
  const int cnt = counts[e];
  const int obase = offs[e];
  const int padc = offs[e+1] - obase;
  const int m0 = blockIdx.y*128;
  if (m0 >= padc) return;
  const int n0 = blockIdx.x*128;
  const u16* B = Ball + (long)e*512*1024;
  const int t = threadIdx.x, lane = t & 63;
  const int w = t >> 6, wm = w >> 1, wn = w & 1;
  const int fr = lane & 15, kg = lane >> 4;
  const int srow = t >> 2, scol = (t & 3) * 8;
  const int s0 = m0 + srow, s1 = m0 + 64 + srow;
  const int tok0 = (s0 < cnt) ? sidx[e*NTOK + s0] : 0;
  const int tok1 = (s1 < cnt) ? sidx[e*NTOK + s1] : 0;
  f32x4 acc[4][4] = {};

  for (int kb = 0; kb < 1024; kb += 32){
    gload_lds16(A + (long)tok0*1024 + kb + scol, &lsA[srow*32 + scol]);
    gload_lds16(A + (long)tok1*1024 + kb + scol, &lsA[(64+srow)*32 + scol]);
    gload_lds16(B + (long)(n0 +      srow)*1024 + kb + scol, &lsB[srow*32 + scol]);
    gload_lds16(B + (long)(n0 + 64 + srow)*1024 + kb + scol, &lsB[(64+srow)*32 + scol]);
    asm volatile("s_waitcnt vmcnt(0)" ::: "memory");
    __syncthreads();
    bf16x8 av[4], bv[4];
#pragma unroll
    for (int i = 0; i < 4; i++){
      av[i] = *(const bf16x8*)&lsA[(wm*64 + i*16 + fr)*32 + kg*8];
      bv[i] = *(const bf16x8*)&lsB[(wn*64 + i*16 + fr)*32 + kg*8];
    }
#pragma unroll
    for (int mi = 0; mi < 4; mi++)
#pragma unroll
      for (int ni = 0; ni < 4; ni++)
        acc[mi][ni] = __builtin_amdgcn_mfma_f32_16x16x32_bf16(av[mi], bv[ni], acc[mi][ni], 0, 0, 0);
    __syncthreads();
  }

  const int r4 = (lane >> 4) * 4;
#pragma unroll
  for (int mi = 0; mi < 4; mi++){
#pragma unroll
    for (int ni = 0; ni < 4; ni++){
      const int col = wn*64 + ni*16 + fr + n0;
#pragma unroll
      for (int r = 0; r < 4; r++){
        const int row = m0 + wm*64 + mi*16 + r4 + r;
        Cg[(long)(obase + row)*512 + col] = f2bf(acc[mi][ni][r]);
      }
    }
  }
}

// Down GEMM dense over slot space: D[slot][1024] bf16; expert from offs
__global__ __launch_bounds__(256)
void gemm_down_slots(const u16* __restrict__ Zg, const u16* __restrict__ Wd,
                     u16* __restrict__ D, const int* __restrict__ offs)
{
  __shared__ u16 lsA[128*32];
  __shared__ u16 lsB[128*32];
  const int m0 = blockIdx.y*128;
  if (m0 >= offs[8]) return;
  int e = 0;
#pragma unroll
  for (int i = 0; i < 7; i++) if (m0 >= offs[i+1]) e = i+1;
  const u16* B = Wd + (long)e*1024*256;
  const int n0 = blockIdx.x*128;
  const int t = threadIdx.x, lane = t & 63;
  const int w = t >> 6, wm = w >> 1, wn = w & 1;
  const int fr = lane & 15, kg = lane >> 4;
  const int srow = t >> 2, scol = (t & 3) * 8;
  f32x4 acc[4][4] = {};

  for (int kb = 0; kb < 256; kb += 32){
    gload_lds16(Zg + (long)(m0 +      srow)*256 + kb + scol, &lsA[srow*32 + scol]);
    gload_lds16(Zg + (long)(m0 + 64 + srow)*256 + kb + scol, &lsA[(64+srow)*32 + scol]);
    gload_lds16(B  + (long)(n0 +      srow)*256 + kb + scol, &lsB[srow*32 + scol]);
    gload_lds16(B  + (long)(n0 + 64 + srow)*256 + kb + scol, &lsB[(64+srow)*32 + scol]);
    asm volatile("s_waitcnt vmcnt(0)" ::: "memory");
    __syncthreads();
    bf16x8 av[4], bv[4];
#pragma unroll
    for (int i = 0; i < 4; i++){
      av[i] = *(const bf16x8*)&lsA[(wm*64 + i*16 + fr)*32 + kg*8];
      bv[i] = *(const bf16x8*)&lsB[(wn*64 + i*16 + fr)*32 + kg*8];
    }
#pragma unroll
    for (int mi = 0; mi < 4; mi++)
#pragma unroll
      for (int ni = 0; ni < 4; ni++)
        acc[mi][ni] = __builtin_amdgcn_mfma_f32_16x16x32_bf16(av[mi], bv[ni], acc[mi][ni], 0, 0, 0);
    __syncthreads();
  }

  const int r4 = (lane >> 4) * 4;
#pragma unroll
  for (int mi = 0; mi < 4; mi++){
#pragma unroll
    for (int ni = 0; ni < 4; ni++){
      const int col = n0 + wn*64 + ni*16 + fr;
#pragma unroll
      for (int r = 0; r < 4; r++){
        const int row = m0 + wm*64 + mi*16 + r4 + r;
        D[(long)row*1024 + col] = f2bf(acc[mi][ni][r]);
      }
    }
  }
}

// ---------------------------------------------------------------------------
__global__ void cast_bf16_k(const float* __restrict__ in, u16* __restrict__ out, long n){
  long i = (long)blockIdx.x*blockDim.x + threadIdx.x;
  long st = (long)gridDim.x*blockDim.x;
  for (; i < n; i += st) out[i] = f2bf(in[i]);
}

__global__ void split_cast_k(const float* __restrict__ in, u16* __restrict__ hi,
                             u16* __restrict__ lo, long n){
  long i = (long)blockIdx.x*blockDim.x + threadIdx.x;
  long st = (long)gridDim.x*blockDim.x;
  for (; i < n; i += st){
    float v = in[i];
    u16 h = f2bf(v);
    hi[i] = h;
    lo[i] = f2bf(v - bf2f(h));
  }
}

__global__ void fold_expert_k(const float* __restrict__ g, const float* __restrict__ u,
                              const float* __restrict__ nw, u16* __restrict__ gu, long n){
  long i = (long)blockIdx.x*blockDim.x + threadIdx.x;
  long st = (long)gridDim.x*blockDim.x;
  for (; i < n; i += st){
    int h  = (int)(i & (Hc - 1));
    int ii = (int)((i >> 10) & (Ic - 1));
    int e  = (int)(i >> 18);
    float wv = nw[e*Hc + h];
    long o = (long)e*(2*Ic*Hc) + (long)ii*Hc + h;
    gu[o]         = f2bf(g[i]*wv);
    gu[o + Ic*Hc] = f2bf(u[i]*wv);
  }
}

__global__ __launch_bounds__(256)
void rmsnorm_split_k(const float* __restrict__ x, const float* __restrict__ w1,
                     u16* __restrict__ o){
  const int row = blockIdx.x, t = threadIdx.x, lane = t & 63, w = t >> 6;
  float4 v = ((const float4*)(x + (long)row*Hc))[t];
  float ss = v.x*v.x + v.y*v.y + v.z*v.z + v.w*v.w;
  for (int off = 32; off; off >>= 1) ss += __shfl_xor(ss, off);
  __shared__ float red[4];
  if (lane == 0) red[w] = ss;
  __syncthreads();
  float rs = rsqrtf((red[0]+red[1]+red[2]+red[3])*(1.f/Hc) + EPSc);
  float4 wv = ((const float4*)w1)[t];
  float f0 = v.x*rs*wv.x, f1 = v.y*rs*wv.y, f2 = v.z*rs*wv.z, f3 = v.w*rs*wv.w;
  ushort4 hv, lv;
  hv.x = f2bf(f0); lv.x = f2bf(f0 - bf2f(hv.x));
  hv.y = f2bf(f1); lv.y = f2bf(f1 - bf2f(hv.y));
  hv.z = f2bf(f2); lv.z = f2bf(f2 - bf2f(hv.z));
  hv.w = f2bf(f3); lv.w = f2bf(f3 - bf2f(hv.w));
  u16* r16 = o + (long)row*2048;
  ((ushort4*)r16)[t] = hv;
  ((ushort4*)(r16 + 1024))[t] = lv;
}

__global__ __launch_bounds__(256)
void rmsnorm_k(const float* __restrict__ x, u16* __restrict__ o1,
               const float* __restrict__ w2, u16* __restrict__ o2){
  const int row = blockIdx.x, t = threadIdx.x, lane = t & 63, w = t >> 6;
  float4 v = ((const float4*)(x + (long)row*Hc))[t];
  float ss = v.x*v.x + v.y*v.y + v.z*v.z + v.w*v.w;
  for (int off = 32; off; off >>= 1) ss += __shfl_xor(ss, off);
  __shared__ float red[4];
  if (lane == 0) red[w] = ss;
  __syncthreads();
  float rs = rsqrtf((red[0]+red[1]+red[2]+red[3])*(1.f/Hc) + EPSc);
  ushort4 ov;
  ov.x = f2bf(v.x*rs); ov.y = f2bf(v.y*rs); ov.z = f2bf(v.z*rs); ov.w = f2bf(v.w*rs);
  ((ushort4*)o1)[(long)row*256 + t] = ov;
  float4 wv = ((const float4*)w2)[t];
  ov.x = f2bf(v.x*rs*wv.x); ov.y = f2bf(v.y*rs*wv.y);
  ov.z = f2bf(v.z*rs*wv.z); ov.w = f2bf(v.w*rs*wv.w);
  ((ushort4*)o2)[(long)row*256 + t] = ov;
}

// masked softmax; writes packed hi|lo P in place. slice = rid>>10, batch = bbase+(slice&3)
__global__ __launch_bounds__(256)
void softmax2_k(float* __restrict__ S, const int* __restrict__ cnt, int bbase){
  const int rid = blockIdx.x;
  const int b = bbase + ((rid >> 10) & 3);
  float* row = S + (long)rid*Lc;
  const int n = cnt[b];
  const int t = threadIdx.x, lane = t & 63, w = t >> 6;
  float4 v = ((const float4*)row)[t];
  const float sc = 0.0625f;
  float vals[4] = {v.x*sc, v.y*sc, v.z*sc, v.w*sc};
  const int c = t*4;
  float m = -3.4e38f;
#pragma unroll
  for (int j = 0; j < 4; j++) if (c + j < n) m = fmaxf(m, vals[j]);
  for (int o = 32; o; o >>= 1) m = fmaxf(m, __shfl_xor(m, o));
  __shared__ float red[8];
  if (lane == 0) red[w] = m;
  __syncthreads();
  m = fmaxf(fmaxf(red[0], red[1]), fmaxf(red[2], red[3]));
  float p[4], s = 0.f;
#pragma unroll
  for (int j = 0; j < 4; j++){ p[j] = (c + j < n) ? __expf(vals[j] - m) : 0.f; s += p[j]; }
  for (int o = 32; o; o >>= 1) s += __shfl_xor(s, o);
  if (lane == 0) red[4 + w] = s;
  __syncthreads();
  const float inv = 1.f / (red[4]+red[5]+red[6]+red[7]);
  ushort4 hv, lv;
  float q0 = p[0]*inv, q1 = p[1]*inv, q2 = p[2]*inv, q3 = p[3]*inv;
  hv.x = f2bf(q0); lv.x = f2bf(q0 - bf2f(hv.x));
  hv.y = f2bf(q1); lv.y = f2bf(q1 - bf2f(hv.y));
  hv.z = f2bf(q2); lv.z = f2bf(q2 - bf2f(hv.z));
  hv.w = f2bf(q3); lv.w = f2bf(q3 - bf2f(hv.w));
  u16* r16 = (u16*)S + (long)rid*2048;
  ((ushort4*)r16)[t] = hv;
  ((ushort4*)(r16 + 1024))[t] = lv;
}

__global__ void zero_k(int* __restrict__ counts, float* __restrict__ wG){
  int i = blockIdx.x*blockDim.x + threadIdx.x;
  if (i < 8) counts[i] = 0;
  for (int j = i; j < MAXSLOTS; j += gridDim.x*blockDim.x) wG[j] = 0.f;
}

// gating: one wave per token; excludes padding tokens; builds per-expert lists
__global__ __launch_bounds__(256)
void gating2_k(const float* __restrict__ x, const float* __restrict__ gnw,
               const float* __restrict__ gw, const int* __restrict__ tcnt,
               int* __restrict__ topi, float* __restrict__ topw,
               int* __restrict__ wPos, int* __restrict__ counts,
               int* __restrict__ sidx){
  const int t = threadIdx.x, lane = t & 63, w = t >> 6;
  const int n = blockIdx.x*4 + w;
  const int b = n >> 10, l = n & 1023;
  if (l >= tcnt[b]) return;          // pad token: no routing
  const float* xr = x + (long)n*Hc;
  float ss = 0.f, sc[8] = {0,0,0,0,0,0,0,0};
  for (int j = 0; j < 16; j++){
    int d = j*64 + lane;
    float xv = xr[d];
    ss += xv*xv;
    float xg = xv * gnw[d];
#pragma unroll
    for (int e = 0; e < 8; e++) sc[e] += xg * gw[e*Hc + d];
  }
  for (int o = 32; o; o >>= 1){
    ss += __shfl_xor(ss, o);
#pragma unroll
    for (int e = 0; e < 8; e++) sc[e] += __shfl_xor(sc[e], o);
  }
  float rs = rsqrtf(ss*(1.f/Hc) + EPSc);
  float m = -3.4e38f;
#pragma unroll
  for (int e = 0; e < 8; e++){ sc[e] *= rs; m = fmaxf(m, sc[e]); }
  float p[8], sum = 0.f;
#pragma unroll
  for (int e = 0; e < 8; e++){ p[e] = __expf(sc[e] - m); sum += p[e]; }
  float inv = 1.f/sum;
#pragma unroll
  for (int e = 0; e < 8; e++) p[e] *= inv;
  int i1 = 0; float v1 = p[0];
#pragma unroll
  for (int e = 1; e < 8; e++) if (p[e] > v1){ v1 = p[e]; i1 = e; }
  int i2 = -1; float v2 = -1.f;
#pragma unroll
  for (int e = 0; e < 8; e++) if (e != i1 && p[e] > v2){ v2 = p[e]; i2 = e; }
  if (lane == 0){
    float dn = v1 + v2 + 1e-20f;
    int p0 = atomicAdd(&counts[i1], 1);
    int p1 = atomicAdd(&counts[i2], 1);
    sidx[i1*NTOK + p0] = n;
    sidx[i2*NTOK + p1] = n;
    topi[2*n] = i1; topi[2*n + 1] = i2;
    wPos[2*n] = p0; wPos[2*n + 1] = p1;
    topw[2*n] = v1/dn; topw[2*n + 1] = v2/dn;
  }
}

__global__ void scan_k(const int* __restrict__ counts, int* __restrict__ offs){
  if (threadIdx.x == 0){
    int o = 0; offs[0] = 0;
    for (int e = 0; e < 8; e++){ o += (counts[e] + 127) & ~127; offs[e+1] = o; }
  }
}

// per-token: global slot positions + scatter weights into wG
__global__ void gpos_k(const int* __restrict__ tcnt, const int* __restrict__ topi,
                       const int* __restrict__ wPos, const float* __restrict__ topw,
                       const int* __restrict__ offs, int* __restrict__ gpos,
                       float* __restrict__ wG){
  int n = blockIdx.x*blockDim.x + threadIdx.x;
  if (n >= NTOK) return;
  int b = n >> 10, l = n & 1023;
  if (l >= tcnt[b]){ gpos[2*n] = 0; gpos[2*n+1] = 0; return; }
  int g0 = offs[topi[2*n]]   + wPos[2*n];
  int g1 = offs[topi[2*n+1]] + wPos[2*n+1];
  gpos[2*n] = g0; gpos[2*n+1] = g1;
  wG[g0] = topw[2*n]; wG[g1] = topw[2*n+1];
}

__global__ void act_shared_k(const u16* __restrict__ gu, u16* __restrict__ z, long n){
  long i = (long)blockIdx.x*blockDim.x + threadIdx.x;
  long st = (long)gridDim.x*blockDim.x;
  for (; i < n; i += st){
    long nn = i >> 9;
    int  ii = (int)(i & (ISc - 1));
    float gv = bf2f(gu[nn*1024 + ii]);
    float uv = bf2f(gu[nn*1024 + ISc + ii]);
    z[i] = f2bf(gv/(1.f + __expf(-gv)) * uv);
  }
}

// slots act: z[s][256] = silu(g)*u*wG[s]
__global__ void act_slots_k(const u16* __restrict__ gu, const float* __restrict__ wG,
                            const int* __restrict__ offs, u16* __restrict__ z){
  long nmax = (long)offs[8]*256;
  long st = (long)gridDim.x*blockDim.x;
  for (long i = (long)blockIdx.x*blockDim.x + threadIdx.x; i < nmax; i += st){
    long s = i >> 8;
    int ii = (int)(i & 255);
    float gv = bf2f(gu[s*512 + ii]);
    float uv = bf2f(gu[s*512 + 256 + ii]);
    z[i] = f2bf(gv/(1.f + __expf(-gv)) * uv * wG[s]);
  }
}

// per-expert act (dense fallback path)
__global__ void act_expert_k(const u16* __restrict__ gu, const int* __restrict__ topi,
                             const float* __restrict__ topw, int e,
                             u16* __restrict__ z, long n){
  long i = (long)blockIdx.x*blockDim.x + threadIdx.x;
  long st = (long)gridDim.x*blockDim.x;
  for (; i < n; i += st){
    long nn = i >> 8;
    int  ii = (int)(i & (Ic - 1));
    float wv = 0.f;
    if      (topi[2*nn]     == e) wv = topw[2*nn];
    else if (topi[2*nn + 1] == e) wv = topw[2*nn + 1];
    float gv = bf2f(gu[nn*512 + ii]);
    float uv = bf2f(gu[nn*512 + Ic + ii]);
    z[i] = f2bf(gv/(1.f + __expf(-gv)) * uv * wv);
  }
}

// final: y = shared + D[g0] + D[g1], out-gate, pad mask
__global__ __launch_bounds__(256)
void final2_k(const float* __restrict__ ysh, const u16* __restrict__ D,
              const int* __restrict__ gpos, const float* __restrict__ ogw,
              const float* __restrict__ ogb, const int* __restrict__ cnt,
              float* __restrict__ out){
  const int t = threadIdx.x, lane = t & 63, w = t >> 6;
  const int n = blockIdx.x*4 + w;
  const int b = n >> 10, l = n & 1023;
  float* outr = out + (long)n*Hc;
  if (l >= cnt[b]){
#pragma unroll
    for (int j = 0; j < 16; j++) outr[j*64 + lane] = 0.f;
    return;
  }
  const float* yr = ysh + (long)n*Hc;
  const u16* d0 = D + (long)gpos[2*n]*1024;
  const u16* d1 = D + (long)gpos[2*n+1]*1024;
  float dot = 0.f, yv[16];
#pragma unroll
  for (int j = 0; j < 16; j++){
    int d = j*64 + lane;
    yv[j] = yr[d] + bf2f(d0[d]) + bf2f(d1[d]);
    dot += yv[j]*ogw[d];
  }
  for (int o = 32; o; o >>= 1) dot += __shfl_xor(dot, o);
  float s = 1.f/(1.f + __expf(-(dot + ogb[0])));
#pragma unroll
  for (int j = 0; j < 16; j++) outr[j*64 + lane] = yv[j]*s;
}

// fallback final (dense routed path already accumulated into y)
__global__ __launch_bounds__(256)
void final_k(const float* __restrict__ y, const float* __restrict__ ogw,
             const float* __restrict__ ogb, const int* __restrict__ cnt,
             float* __restrict__ out){
  const int t = threadIdx.x, lane = t & 63, w = t >> 6;
  const int n = blockIdx.x*4 + w;
  const int b = n >> 10, l = n & 1023;
  const bool pad = l >= cnt[b];
  const float* yr = y + (long)n*Hc;
  float dot = 0.f, yv[16];
#pragma unroll
  for (int j = 0; j < 16; j++){
    int d = j*64 + lane;
    yv[j] = yr[d];
    dot += yv[j]*ogw[d];
  }
  for (int o = 32; o; o >>= 1) dot += __shfl_xor(dot, o);
  float s = 1.f/(1.f + __expf(-(dot + ogb[0])));
  float* outr = out + (long)n*Hc;
#pragma unroll
  for (int j = 0; j < 16; j++){
    int d = j*64 + lane;
    outr[d] = pad ? 0.f : yv[j]*s;
  }
}

__global__ void sentinel_k(float* out){ out[0] = 1.0e9f; }

// ---------------------------------------------------------------------------
extern "C" void kernel_launch(void* const* d_in, const int* in_sizes, int n_in,
                              void* d_out, int out_size, void* d_ws, size_t ws_size,
                              hipStream_t stream){
  const float* hidden  = (const float*)d_in[0];
  const int*   cnt     = (const int*)  d_in[1];
  const float* ctx_nw  = (const float*)d_in[2];
  const float* Wqkv    = (const float*)d_in[3];
  const float* in_b    = (const float*)d_in[4];
  const float* Woutp   = (const float*)d_in[5];
  const float* out_b   = (const float*)d_in[6];
  const float* gate_nw = (const float*)d_in[7];
  const float* gate_w  = (const float*)d_in[8];
  const float* exp_nw  = (const float*)d_in[9];
  const float* Weg     = (const float*)d_in[10];
  const float* Weu     = (const float*)d_in[11];
  const float* Wed     = (const float*)d_in[12];
  const float* sh_nw   = (const float*)d_in[13];
  const float* Wsg     = (const float*)d_in[14];
  const float* Wsu     = (const float*)d_in[15];
  const float* Wsd     = (const float*)d_in[16];
  const float* ogw     = (const float*)d_in[17];
  const float* ogb     = (const float*)d_in[18];
  float* out = (float*)d_out;

  const size_t MB = 1024*1024;
  char* ws = (char*)d_ws;
  size_t off = 0;
  auto alloc = [&](size_t bytes)->char*{
    char* p = ws + off; off += (bytes + 255) & ~(size_t)255; return p;
  };
  // weights
  u16* wWqH  = (u16*)alloc((size_t)3072*1024*2);
  u16* wWqL  = (u16*)alloc((size_t)3072*1024*2);
  u16* wWoH  = (u16*)alloc((size_t)1024*1024*2);
  u16* wWoL  = (u16*)alloc((size_t)1024*1024*2);
  u16* wWgu  = (u16*)alloc((size_t)Ec*2*Ic*Hc*2);
  u16* wWd   = (u16*)alloc((size_t)Ec*Hc*Ic*2);    // [E][1024][256]
  u16* wWsgu = (u16*)alloc((size_t)2*ISc*Hc*2);
  u16* wWsd  = (u16*)alloc((size_t)Hc*ISc*2);
  int*   wTopI = (int*)  alloc((size_t)NTOK*2*4);
  float* wTopW = (float*)alloc((size_t)NTOK*2*4);
  int*   wPos  = (int*)  alloc((size_t)NTOK*2*4);
  int*   wGpos = (int*)  alloc((size_t)NTOK*2*4);
  int*   wSidx = (int*)  alloc((size_t)Ec*NTOK*4);
  float* wG    = (float*)alloc((size_t)MAXSLOTS*4);
  int*   wCnts = (int*)  alloc(64);
  int*   wOffs = (int*)  alloc(64);
  // arenas
  char* P1 = alloc(32*MB);   // nx packed -> ctx packed -> Y f32 (shared)
  char* P2 = alloc(32*MB);   // Qp packed -> Xhat bf16 + Sx bf16
  char* P3 = alloc(32*MB);   // Kp packed -> X f32 -> GUg + Zg
  char* P4 = alloc(32*MB);   // Vtp packed -> shGU + Zs
  size_t fixed = off;
  const bool big = (fixed + 64*MB) <= ws_size;
  char* P5 = alloc(big ? 64*MB : 16*MB);  // S f32 -> D bf16 (big)
  if (off > ws_size){ sentinel_k<<<1,1,0,stream>>>(out); return; }

  u16*   wNx   = (u16*)P1;
  u16*   wCtx  = (u16*)P1;
  float* wY    = (float*)P1;
  u16*   wQp   = (u16*)P2;
  u16*   wXhat = (u16*)P2;
  u16*   wSx   = (u16*)(P2 + 16*MB);
  u16*   wKp   = (u16*)P3;
  float* wX    = (float*)P3;
  u16*   wGUg  = (u16*)P3;               // big: [MAXSLOTS][512]
  u16*   wZg   = (u16*)(P3 + 18*MB);     // big: [MAXSLOTS][256]
  u16*   wGUe  = (u16*)P3;               // small fallback
  u16*   wZe   = (u16*)(P3 + 8*MB);
  u16*   wVtp  = (u16*)P4;
  u16*   wGUs  = (u16*)P4;
  u16*   wZs   = (u16*)(P4 + 16*MB);
  float* wS    = (float*)P5;
  u16*   wD    = (u16*)P5;               // big: [MAXSLOTS][1024] bf16 (after attn)

  // 1) weight prep
  split_cast_k<<<4096, 256, 0, stream>>>(Wqkv,  wWqH, wWqL, (long)3072*1024);
  split_cast_k<<<2048, 256, 0, stream>>>(Woutp, wWoH, wWoL, (long)1024*1024);
  cast_bf16_k<<<2048, 256, 0, stream>>>(Wed, wWd, (long)Ec*Hc*Ic);
  cast_bf16_k<<<1024, 256, 0, stream>>>(Wsg, wWsgu,                (long)ISc*Hc);
  cast_bf16_k<<<1024, 256, 0, stream>>>(Wsu, wWsgu + (long)ISc*Hc, (long)ISc*Hc);
  cast_bf16_k<<<1024, 256, 0, stream>>>(Wsd, wWsd, (long)Hc*ISc);
  fold_expert_k<<<2048, 256, 0, stream>>>(Weg, Weu, exp_nw, wWgu, (long)Ec*Ic*Hc);

  // 2) pre-attn norm (split) + Q&K merged projection (z=2) + V projection
  rmsnorm_split_k<<<NTOK, 256, 0, stream>>>(hidden, ctx_nw, wNx);
  gemm3<0, 1, 0><<<dim3(8, 64, 2), 256, 0, stream>>>(
      wNx, wNx + 1024, wWqH, wWqL, wQp, in_b, nullptr,
      NTOK, 1024, 1024, 2048, 1024, 2048,
      0, 0, (long)1024*1024, 0, (long)16*1024*1024, 0,
      1024, 1024, nullptr, 0);
  gemm3<3, 1, 0><<<dim3(8, 64, 1), 256, 0, stream>>>(
      wNx, wNx + 1024, wWqH + (long)2048*1024, wWqL + (long)2048*1024, wVtp,
      in_b + 2048, nullptr, NTOK, 1024, 1024, 2048, 1024, 0,
      0, 0, 0, 0, 0, 0, 0, 0, nullptr, 0);

  // 3) attention: z = (head<<2)|batch_in_group; N-skip QK, K-clamp PV
  const int zper = big ? 16 : 4;
  const int ngroups = 32 / zper;
  for (int g = 0; g < ngroups; g++){
    const int hf    = big ? g : (g >> 2);
    const int hbase = big ? 0 : (g & 3);
    const int bbase = hf*4;
    const long tokoff = (long)hf*4*Lc*2048;
    const u16* Qb = wQp + tokoff + hbase*HDc;
    const u16* Kb = wKp + tokoff + hbase*HDc;
    gemm3<1, 0, 1><<<dim3(8, 8, zper), 256, 0, stream>>>(
        Qb, Qb + 1024, Kb, Kb + 1024, wS, nullptr, nullptr,
        Lc, Lc, HDc, 2048, 2048, Lc,
        (long)Lc*2048, (long)HDc,
        (long)Lc*2048, (long)HDc,
        (long)Lc*Lc,   (long)4*Lc*Lc,
        0, 0, cnt, bbase);
    softmax2_k<<<zper*1024, 256, 0, stream>>>(wS, cnt, bbase);
    const u16* Vb = wVtp + (long)hf*4*NHc*HDc*2048 + (long)hbase*HDc*2048;
    u16* Cb = wCtx + tokoff + hbase*HDc;
    gemm3<0, 0, 2><<<dim3(2, 8, zper), 256, 0, stream>>>(
        (const u16*)wS, (const u16*)wS + 1024, Vb, Vb + 1024, Cb, nullptr, nullptr,
        Lc, HDc, Lc, 2048, 2048, 2048,
        (long)Lc*2048,     (long)4*Lc*2048,
        (long)NHc*HDc*2048,(long)HDc*2048,
        (long)Lc*2048,     (long)HDc,
        1024, 0, cnt, bbase);
  }

  // 4) out-proj + bias + residual -> X f32
  gemm3<2, 1, 0><<<dim3(8, 64, 1), 256, 0, stream>>>(
      wCtx, wCtx + 1024, wWoH, wWoL, wX, out_b, hidden,
      NTOK, 1024, 1024, 2048, 1024, 1024,
      0, 0, 0, 0, 0, 0, 0, 0, nullptr, 0);

  // 5) gating (sparse lists) + post-norms
  zero_k<<<68, 256, 0, stream>>>(wCnts, wG);
  gating2_k<<<NTOK/4, 256, 0, stream>>>(wX, gate_nw, gate_w, cnt,
                                        wTopI, wTopW, wPos, wCnts, wSidx);
  scan_k<<<1, 64, 0, stream>>>(wCnts, wOffs);
  gpos_k<<<NTOK/256, 256, 0, stream>>>(cnt, wTopI, wPos, wTopW, wOffs, wGpos, wG);
  rmsnorm_k<<<NTOK, 256, 0, stream>>>(wX, wXhat, sh_nw, wSx);

  // 6) shared experts -> Y
  gemm_bt<0><<<dim3(8, 64, 1), 256, 0, stream>>>(
      wSx, wWsgu, wGUs, NTOK, 2*ISc, 1024, 1024, 1024, 2*ISc, 0, 0, 0);
  act_shared_k<<<4096, 256, 0, stream>>>(wGUs, wZs, (long)NTOK*ISc);
  gemm_bt<1><<<dim3(8, 64, 1), 256, 0, stream>>>(
      wZs, wWsd, wY, NTOK, 1024, ISc, ISc, ISc, 1024, 0, 0, 0);

  // 7) routed experts
  if (big){
    gemm_gu_gather<<<dim3(4, 64, Ec), 256, 0, stream>>>(
        wXhat, wWgu, wGUg, wSidx, wCnts, wOffs);
    act_slots_k<<<2048, 256, 0, stream>>>(wGUg, wG, wOffs, wZg);
    gemm_down_slots<<<dim3(8, MAXSLOTS/128, 1), 256, 0, stream>>>(
        wZg, wWd, wD, wOffs);
    final2_k<<<NTOK/4, 256, 0, stream>>>(wY, wD, wGpos, ogw, ogb, cnt, out);
  } else {
    for (int e = 0; e < Ec; e++){
      gemm_bt<0><<<dim3(4, 64, 1), 256, 0, stream>>>(
          wXhat, wWgu + (long)e*2*Ic*Hc, wGUe, NTOK, 2*Ic, 1024, 1024, 1024, 2*Ic, 0,0,0);
      act_expert_k<<<2048, 256, 0, stream>>>(wGUe, wTopI, wTopW, e, wZe, (long)NTOK*Ic);
      gemm_bt<2><<<dim3(8, 64, 1), 256, 0, stream>>>(
          wZe, wWd + (long)e*Hc*Ic, wY, NTOK, 1024, Ic, Ic, Ic, 1024, 0,0,0);
    }
    final_k<<<NTOK/4, 256, 0, stream>>>(wY, ogw, ogb, cnt, out);
  }
}

// Round 7
// 733.586 us; speedup vs baseline: 1.9156x; 1.0758x over previous
//
#include <hip/hip_runtime.h>
#include <hip/hip_bf16.h>

typedef unsigned short u16;
typedef unsigned int   u32;
typedef short bf16x8 __attribute__((ext_vector_type(8)));
typedef float f32x4  __attribute__((ext_vector_type(4)));

#define DEV static __device__ __forceinline__

#define Bc 8
#define Lc 1024
#define Hc 1024
#define Ec 8
#define Ic 256
#define ISc 512
#define NHc 4
#define HDc 256
#define NTOK 8192
#define EPSc 1e-6f
#define MAXSLOTS 17408

DEV u16 f2bf(float f){
  u32 u = __float_as_uint(f);
  return (u16)((u + 0x7fffu + ((u >> 16) & 1u)) >> 16);
}
DEV float bf2f(u16 h){ return __uint_as_float(((u32)h) << 16); }

DEV void gload_lds16(const void* g, void* l){
  __builtin_amdgcn_global_load_lds((const __attribute__((address_space(1))) u32*)g,
                                   (__attribute__((address_space(3))) u32*)l, 16, 0, 0);
}

// ---------------------------------------------------------------------------
// Split-precision NT GEMM: C = (Ahi+Alo)·(Bhi+Blo)^T ≈ AhiBhi + AhiBlo + AloBhi
// EPI: 0 = packed hi|lo store (lo at +loOffC), 1 = f32, 2 = f32 acc+bias+Res,
//      3 = V-transpose packed hi|lo
// SKIP: 0 none; 1 = attn QK: skip if m0>=tc[b] or n0>=tc[b]
//       2 = attn PV: skip if m0>=tc[b], clamp K to ceil32(tc[b])
//       3 = token rows (M=8192): skip if (m0&1023)>=tc[m0>>10]
// SWZ:  0 default (x=n,y=m); 1 = slice->XCD swizzle (gridDim.z==16);
//       2 = transposed grid (x=m,y=n) -> A-panel per XCD
// ---------------------------------------------------------------------------
template<int EPI, int BIAS, int SKIP, int SWZ>
__global__ __launch_bounds__(256)
void gemm3(const u16* __restrict__ Ahi, const u16* __restrict__ Alo,
           const u16* __restrict__ Bhi, const u16* __restrict__ Blo,
           void* __restrict__ Cv, const float* __restrict__ bias,
           const float* __restrict__ Res,
           int M, int N, int K, int lda, int ldb, int ldc,
           long sAin, long sAout, long sBin, long sBout, long sCin, long sCout,
           int loOffC, int biasStride, const int* __restrict__ tc, int bbase)
{
  __shared__ u16 lsAh[128*32];
  __shared__ u16 lsAl[128*32];
  __shared__ u16 lsBh[128*32];
  __shared__ u16 lsBl[128*32];
  int m_i, n_i, z;
  if (SWZ == 1){
    const int NB = gridDim.x*gridDim.y;
    const int L = blockIdx.x + gridDim.x*(blockIdx.y + gridDim.y*blockIdx.z);
    const int r = L & 7, k = L >> 3;
    z = r + 8*(k / NB);
    const int idx = k % NB;
    n_i = idx % gridDim.x; m_i = idx / gridDim.x;
  } else if (SWZ == 2){
    m_i = blockIdx.x; n_i = blockIdx.y; z = blockIdx.z;
  } else {
    n_i = blockIdx.x; m_i = blockIdx.y; z = blockIdx.z;
  }
  const int n0 = n_i*128, m0 = m_i*128;
  const int zin = z & 3, zout = z >> 2;
  if (SKIP == 1){ const int c = tc[bbase + zin]; if (m0 >= c || n0 >= c) return; }
  if (SKIP == 2){ const int c = tc[bbase + zin]; if (m0 >= c) return;
                  const int kl = (c + 31) & ~31; K = K < kl ? K : kl; }
  if (SKIP == 3){ if ((m0 & 1023) >= tc[m0 >> 10]) return; }
  const long aoff = (long)zin*sAin + (long)zout*sAout;
  const long boff = (long)zin*sBin + (long)zout*sBout;
  const long coff = (long)zin*sCin + (long)zout*sCout;
  const u16* Ahb = Ahi + aoff;
  const u16* Alb = Alo + aoff;
  const u16* Bhb = Bhi + boff;
  const u16* Blb = Blo + boff;
  const int t = threadIdx.x, lane = t & 63;
  const int w = t >> 6, wm = w >> 1, wn = w & 1;
  const int fr = lane & 15, kg = lane >> 4;
  const int srow = t >> 2, scol = (t & 3) * 8;
  f32x4 acc[4][4] = {};

  for (int kb = 0; kb < K; kb += 32){
    gload_lds16(Ahb + (long)(m0 +      srow)*lda + kb + scol, &lsAh[srow*32 + scol]);
    gload_lds16(Ahb + (long)(m0 + 64 + srow)*lda + kb + scol, &lsAh[(64+srow)*32 + scol]);
    gload_lds16(Alb + (long)(m0 +      srow)*lda + kb + scol, &lsAl[srow*32 + scol]);
    gload_lds16(Alb + (long)(m0 + 64 + srow)*lda + kb + scol, &lsAl[(64+srow)*32 + scol]);
    gload_lds16(Bhb + (long)(n0 +      srow)*ldb + kb + scol, &lsBh[srow*32 + scol]);
    gload_lds16(Bhb + (long)(n0 + 64 + srow)*ldb + kb + scol, &lsBh[(64+srow)*32 + scol]);
    gload_lds16(Blb + (long)(n0 +      srow)*ldb + kb + scol, &lsBl[srow*32 + scol]);
    gload_lds16(Blb + (long)(n0 + 64 + srow)*ldb + kb + scol, &lsBl[(64+srow)*32 + scol]);
    asm volatile("s_waitcnt vmcnt(0)" ::: "memory");
    __syncthreads();
    bf16x8 ah[4], al[4], bh[4], bl[4];
#pragma unroll
    for (int i = 0; i < 4; i++){
      ah[i] = *(const bf16x8*)&lsAh[(wm*64 + i*16 + fr)*32 + kg*8];
      al[i] = *(const bf16x8*)&lsAl[(wm*64 + i*16 + fr)*32 + kg*8];
      bh[i] = *(const bf16x8*)&lsBh[(wn*64 + i*16 + fr)*32 + kg*8];
      bl[i] = *(const bf16x8*)&lsBl[(wn*64 + i*16 + fr)*32 + kg*8];
    }
#pragma unroll
    for (int mi = 0; mi < 4; mi++)
#pragma unroll
      for (int ni = 0; ni < 4; ni++){
        acc[mi][ni] = __builtin_amdgcn_mfma_f32_16x16x32_bf16(ah[mi], bh[ni], acc[mi][ni], 0, 0, 0);
        acc[mi][ni] = __builtin_amdgcn_mfma_f32_16x16x32_bf16(ah[mi], bl[ni], acc[mi][ni], 0, 0, 0);
        acc[mi][ni] = __builtin_amdgcn_mfma_f32_16x16x32_bf16(al[mi], bh[ni], acc[mi][ni], 0, 0, 0);
      }
    __syncthreads();
  }

  const int r4 = (lane >> 4) * 4;
#pragma unroll
  for (int mi = 0; mi < 4; mi++){
#pragma unroll
    for (int ni = 0; ni < 4; ni++){
      const int col = n0 + wn*64 + ni*16 + fr;
      const float bb = BIAS ? bias[zin*biasStride + col] : 0.f;
#pragma unroll
      for (int r = 0; r < 4; r++){
        const int row = m0 + wm*64 + mi*16 + r4 + r;
        float v = acc[mi][ni][r] + bb;
        if (EPI == 0){
          u16 hv = f2bf(v), lv = f2bf(v - bf2f(hv));
          long idx = coff + (long)row*ldc + col;
          ((u16*)Cv)[idx] = hv;
          ((u16*)Cv)[idx + loOffC] = lv;
        } else if (EPI == 1){
          ((float*)Cv)[coff + (long)row*ldc + col] = v;
        } else if (EPI == 2){
          long idx = coff + (long)row*ldc + col;
          ((float*)Cv)[idx] = v + Res[idx];
        } else {
          u16 hv = f2bf(v), lv = f2bf(v - bf2f(hv));
          int b = row >> 10, q = row & 1023;
          int h = col >> 8, d = col & 255;
          long o = ((long)(b*NHc + h)*HDc + d)*2048 + q;
          ((u16*)Cv)[o] = hv;
          ((u16*)Cv)[o + 1024] = lv;
        }
      }
    }
  }
}

// ---------------------------------------------------------------------------
// Plain bf16 NT GEMM. EPI: 0 bf16, 1 f32, 2 f32 +=. SKIP 3 = pad-row skip.
// SWZ 2 = transposed grid (x=m,y=n).
template<int EPI, int SKIP, int SWZ>
__global__ __launch_bounds__(256)
void gemm_bt(const u16* __restrict__ A, const u16* __restrict__ B,
             void* __restrict__ Cv,
             int M, int N, int K, int lda, int ldb, int ldc,
             long sAz, long sBz, long sCz, const int* __restrict__ tc)
{
  __shared__ u16 lsA[128*32];
  __shared__ u16 lsB[128*32];
  int m_i, n_i;
  if (SWZ == 2){ m_i = blockIdx.x; n_i = blockIdx.y; }
  else         { n_i = blockIdx.x; m_i = blockIdx.y; }
  const int z = blockIdx.z;
  const int n0 = n_i*128, m0 = m_i*128;
  if (SKIP == 3){ if ((m0 & 1023) >= tc[m0 >> 10]) return; }
  const u16* Ab = A + (long)z*sAz;
  const u16* Bb = B + (long)z*sBz;
  const int t = threadIdx.x, lane = t & 63;
  const int w = t >> 6, wm = w >> 1, wn = w & 1;
  const int fr = lane & 15, kg = lane >> 4;
  const int srow = t >> 2, scol = (t & 3) * 8;
  f32x4 acc[4][4] = {};

  for (int kb = 0; kb < K; kb += 32){
    gload_lds16(Ab + (long)(m0 +      srow)*lda + kb + scol, &lsA[srow*32 + scol]);
    gload_lds16(Ab + (long)(m0 + 64 + srow)*lda + kb + scol, &lsA[(64+srow)*32 + scol]);
    gload_lds16(Bb + (long)(n0 +      srow)*ldb + kb + scol, &lsB[srow*32 + scol]);
    gload_lds16(Bb + (long)(n0 + 64 + srow)*ldb + kb + scol, &lsB[(64+srow)*32 + scol]);
    asm volatile("s_waitcnt vmcnt(0)" ::: "memory");
    __syncthreads();
    bf16x8 av[4], bv[4];
#pragma unroll
    for (int i = 0; i < 4; i++){
      av[i] = *(const bf16x8*)&lsA[(wm*64 + i*16 + fr)*32 + kg*8];
      bv[i] = *(const bf16x8*)&lsB[(wn*64 + i*16 + fr)*32 + kg*8];
    }
#pragma unroll
    for (int mi = 0; mi < 4; mi++)
#pragma unroll
      for (int ni = 0; ni < 4; ni++)
        acc[mi][ni] = __builtin_amdgcn_mfma_f32_16x16x32_bf16(av[mi], bv[ni], acc[mi][ni], 0, 0, 0);
    __syncthreads();
  }

  const int r4 = (lane >> 4) * 4;
#pragma unroll
  for (int mi = 0; mi < 4; mi++){
#pragma unroll
    for (int ni = 0; ni < 4; ni++){
      const int col = n0 + wn*64 + ni*16 + fr;
#pragma unroll
      for (int r = 0; r < 4; r++){
        const int row = m0 + wm*64 + mi*16 + r4 + r;
        const long idx = (long)z*sCz + (long)row*ldc + col;
        float v = acc[mi][ni][r];
        if      (EPI == 0) ((u16*)Cv)[idx]   = f2bf(v);
        else if (EPI == 1) ((float*)Cv)[idx] = v;
        else               ((float*)Cv)[idx] += v;
      }
    }
  }
}

// ---------------------------------------------------------------------------
// Gathered GU GEMM: per expert e, rows = tokens from sidx
__global__ __launch_bounds__(256)
void gemm_gu_gather(const u16* __restrict__ A, const u16* __restrict__ Ball,
                    u16* __restrict__ Cg, const int* __restrict__ sidx,
                    const int* __restrict__ counts, const int* __restrict__ offs)
{
  __shared__ u16 lsA[128*32];
  __shared__ u16 lsB[128*32];
  const int e = blockIdx.z;
  const int cnt = counts[e];
  const int obase = offs[e];
  const int padc = offs[e+1] - obase;
  const int m0 = blockIdx.y*128;
  if (m0 >= padc) return;
  const int n0 = blockIdx.x*128;
  const u16* B = Ball + (long)e*512*1024;
  const int t = threadIdx.x, lane = t & 63;
  const int w = t >> 6, wm = w >> 1, wn = w & 1;
  const int fr = lane & 15, kg = lane >> 4;
  const int srow = t >> 2, scol = (t & 3) * 8;
  const int s0 = m0 + srow, s1 = m0 + 64 + srow;
  const int tok0 = (s0 < cnt) ? sidx[e*NTOK + s0] : 0;
  const int tok1 = (s1 < cnt) ? sidx[e*NTOK + s1] : 0;
  f32x4 acc[4][4] = {};

  for (int kb = 0; kb < 1024; kb += 32){
    gload_lds16(A + (long)tok0*1024 + kb + scol, &lsA[srow*32 + scol]);
    gload_lds16(A + (long)tok1*1024 + kb + scol, &lsA[(64+srow)*32 + scol]);
    gload_lds16(B + (long)(n0 +      srow)*1024 + kb + scol, &lsB[srow*32 + scol]);
    gload_lds16(B + (long)(n0 + 64 + srow)*1024 + kb + scol, &lsB[(64+srow)*32 + scol]);
    asm volatile("s_waitcnt vmcnt(0)" ::: "memory");
    __syncthreads();
    bf16x8 av[4], bv[4];
#pragma unroll
    for (int i = 0; i < 4; i++){
      av[i] = *(const bf16x8*)&lsA[(wm*64 + i*16 + fr)*32 + kg*8];
      bv[i] = *(const bf16x8*)&lsB[(wn*64 + i*16 + fr)*32 + kg*8];
    }
#pragma unroll
    for (int mi = 0; mi < 4; mi++)
#pragma unroll
      for (int ni = 0; ni < 4; ni++)
        acc[mi][ni] = __builtin_amdgcn_mfma_f32_16x16x32_bf16(av[mi], bv[ni], acc[mi][ni], 0, 0, 0);
    __syncthreads();
  }

  const int r4 = (lane >> 4) * 4;
#pragma unroll
  for (int mi = 0; mi < 4; mi++){
#pragma unroll
    for (int ni = 0; ni < 4; ni++){
      const int col = wn*64 + ni*16 + fr + n0;
#pragma unroll
      for (int r = 0; r < 4; r++){
        const int row = m0 + wm*64 + mi*16 + r4 + r;
        Cg[(long)(obase + row)*512 + col] = f2bf(acc[mi][ni][r]);
      }
    }
  }
}

// Down GEMM dense over slot space
__global__ __launch_bounds__(256)
void gemm_down_slots(const u16* __restrict__ Zg, const u16* __restrict__ Wd,
                     u16* __restrict__ D, const int* __restrict__ offs)
{
  __shared__ u16 lsA[128*32];
  __shared__ u16 lsB[128*32];
  const int m0 = blockIdx.y*128;
  if (m0 >= offs[8]) return;
  int e = 0;
#pragma unroll
  for (int i = 0; i < 7; i++) if (m0 >= offs[i+1]) e = i+1;
  const u16* B = Wd + (long)e*1024*256;
  const int n0 = blockIdx.x*128;
  const int t = threadIdx.x, lane = t & 63;
  const int w = t >> 6, wm = w >> 1, wn = w & 1;
  const int fr = lane & 15, kg = lane >> 4;
  const int srow = t >> 2, scol = (t & 3) * 8;
  f32x4 acc[4][4] = {};

  for (int kb = 0; kb < 256; kb += 32){
    gload_lds16(Zg + (long)(m0 +      srow)*256 + kb + scol, &lsA[srow*32 + scol]);
    gload_lds16(Zg + (long)(m0 + 64 + srow)*256 + kb + scol, &lsA[(64+srow)*32 + scol]);
    gload_lds16(B  + (long)(n0 +      srow)*256 + kb + scol, &lsB[srow*32 + scol]);
    gload_lds16(B  + (long)(n0 + 64 + srow)*256 + kb + scol, &lsB[(64+srow)*32 + scol]);
    asm volatile("s_waitcnt vmcnt(0)" ::: "memory");
    __syncthreads();
    bf16x8 av[4], bv[4];
#pragma unroll
    for (int i = 0; i < 4; i++){
      av[i] = *(const bf16x8*)&lsA[(wm*64 + i*16 + fr)*32 + kg*8];
      bv[i] = *(const bf16x8*)&lsB[(wn*64 + i*16 + fr)*32 + kg*8];
    }
#pragma unroll
    for (int mi = 0; mi < 4; mi++)
#pragma unroll
      for (int ni = 0; ni < 4; ni++)
        acc[mi][ni] = __builtin_amdgcn_mfma_f32_16x16x32_bf16(av[mi], bv[ni], acc[mi][ni], 0, 0, 0);
    __syncthreads();
  }

  const int r4 = (lane >> 4) * 4;
#pragma unroll
  for (int mi = 0; mi < 4; mi++){
#pragma unroll
    for (int ni = 0; ni < 4; ni++){
      const int col = n0 + wn*64 + ni*16 + fr;
#pragma unroll
      for (int r = 0; r < 4; r++){
        const int row = m0 + wm*64 + mi*16 + r4 + r;
        D[(long)row*1024 + col] = f2bf(acc[mi][ni][r]);
      }
    }
  }
}

// ---------------------------------------------------------------------------
__global__ void cast_bf16_k(const float* __restrict__ in, u16* __restrict__ out, long n){
  long i = (long)blockIdx.x*blockDim.x + threadIdx.x;
  long st = (long)gridDim.x*blockDim.x;
  for (; i < n; i += st) out[i] = f2bf(in[i]);
}

__global__ void split_cast_k(const float* __restrict__ in, u16* __restrict__ hi,
                             u16* __restrict__ lo, long n){
  long i = (long)blockIdx.x*blockDim.x + threadIdx.x;
  long st = (long)gridDim.x*blockDim.x;
  for (; i < n; i += st){
    float v = in[i];
    u16 h = f2bf(v);
    hi[i] = h;
    lo[i] = f2bf(v - bf2f(h));
  }
}

__global__ void fold_expert_k(const float* __restrict__ g, const float* __restrict__ u,
                              const float* __restrict__ nw, u16* __restrict__ gu, long n){
  long i = (long)blockIdx.x*blockDim.x + threadIdx.x;
  long st = (long)gridDim.x*blockDim.x;
  for (; i < n; i += st){
    int h  = (int)(i & (Hc - 1));
    int ii = (int)((i >> 10) & (Ic - 1));
    int e  = (int)(i >> 18);
    float wv = nw[e*Hc + h];
    long o = (long)e*(2*Ic*Hc) + (long)ii*Hc + h;
    gu[o]         = f2bf(g[i]*wv);
    gu[o + Ic*Hc] = f2bf(u[i]*wv);
  }
}

__global__ __launch_bounds__(256)
void rmsnorm_split_k(const float* __restrict__ x, const float* __restrict__ w1,
                     u16* __restrict__ o){
  const int row = blockIdx.x, t = threadIdx.x, lane = t & 63, w = t >> 6;
  float4 v = ((const float4*)(x + (long)row*Hc))[t];
  float ss = v.x*v.x + v.y*v.y + v.z*v.z + v.w*v.w;
  for (int off = 32; off; off >>= 1) ss += __shfl_xor(ss, off);
  __shared__ float red[4];
  if (lane == 0) red[w] = ss;
  __syncthreads();
  float rs = rsqrtf((red[0]+red[1]+red[2]+red[3])*(1.f/Hc) + EPSc);
  float4 wv = ((const float4*)w1)[t];
  float f0 = v.x*rs*wv.x, f1 = v.y*rs*wv.y, f2 = v.z*rs*wv.z, f3 = v.w*rs*wv.w;
  ushort4 hv, lv;
  hv.x = f2bf(f0); lv.x = f2bf(f0 - bf2f(hv.x));
  hv.y = f2bf(f1); lv.y = f2bf(f1 - bf2f(hv.y));
  hv.z = f2bf(f2); lv.z = f2bf(f2 - bf2f(hv.z));
  hv.w = f2bf(f3); lv.w = f2bf(f3 - bf2f(hv.w));
  u16* r16 = o + (long)row*2048;
  ((ushort4*)r16)[t] = hv;
  ((ushort4*)(r16 + 1024))[t] = lv;
}

__global__ __launch_bounds__(256)
void rmsnorm_k(const float* __restrict__ x, u16* __restrict__ o1,
               const float* __restrict__ w2, u16* __restrict__ o2){
  const int row = blockIdx.x, t = threadIdx.x, lane = t & 63, w = t >> 6;
  float4 v = ((const float4*)(x + (long)row*Hc))[t];
  float ss = v.x*v.x + v.y*v.y + v.z*v.z + v.w*v.w;
  for (int off = 32; off; off >>= 1) ss += __shfl_xor(ss, off);
  __shared__ float red[4];
  if (lane == 0) red[w] = ss;
  __syncthreads();
  float rs = rsqrtf((red[0]+red[1]+red[2]+red[3])*(1.f/Hc) + EPSc);
  ushort4 ov;
  ov.x = f2bf(v.x*rs); ov.y = f2bf(v.y*rs); ov.z = f2bf(v.z*rs); ov.w = f2bf(v.w*rs);
  ((ushort4*)o1)[(long)row*256 + t] = ov;
  float4 wv = ((const float4*)w2)[t];
  ov.x = f2bf(v.x*rs*wv.x); ov.y = f2bf(v.y*rs*wv.y);
  ov.z = f2bf(v.z*rs*wv.z); ov.w = f2bf(v.w*rs*wv.w);
  ((ushort4*)o2)[(long)row*256 + t] = ov;
}

// masked softmax; skips padded q rows. slice = rid>>10, batch = bbase+(slice&3)
__global__ __launch_bounds__(256)
void softmax2_k(float* __restrict__ S, const int* __restrict__ cnt, int bbase){
  const int rid = blockIdx.x;
  const int b = bbase + ((rid >> 10) & 3);
  const int n = cnt[b];
  if ((rid & 1023) >= n) return;     // padded query row: never consumed
  float* row = S + (long)rid*Lc;
  const int t = threadIdx.x, lane = t & 63, w = t >> 6;
  float4 v = ((const float4*)row)[t];
  const float sc = 0.0625f;
  float vals[4] = {v.x*sc, v.y*sc, v.z*sc, v.w*sc};
  const int c = t*4;
  float m = -3.4e38f;
#pragma unroll
  for (int j = 0; j < 4; j++) if (c + j < n) m = fmaxf(m, vals[j]);
  for (int o = 32; o; o >>= 1) m = fmaxf(m, __shfl_xor(m, o));
  __shared__ float red[8];
  if (lane == 0) red[w] = m;
  __syncthreads();
  m = fmaxf(fmaxf(red[0], red[1]), fmaxf(red[2], red[3]));
  float p[4], s = 0.f;
#pragma unroll
  for (int j = 0; j < 4; j++){ p[j] = (c + j < n) ? __expf(vals[j] - m) : 0.f; s += p[j]; }
  for (int o = 32; o; o >>= 1) s += __shfl_xor(s, o);
  if (lane == 0) red[4 + w] = s;
  __syncthreads();
  const float inv = 1.f / (red[4]+red[5]+red[6]+red[7]);
  ushort4 hv, lv;
  float q0 = p[0]*inv, q1 = p[1]*inv, q2 = p[2]*inv, q3 = p[3]*inv;
  hv.x = f2bf(q0); lv.x = f2bf(q0 - bf2f(hv.x));
  hv.y = f2bf(q1); lv.y = f2bf(q1 - bf2f(hv.y));
  hv.z = f2bf(q2); lv.z = f2bf(q2 - bf2f(hv.z));
  hv.w = f2bf(q3); lv.w = f2bf(q3 - bf2f(hv.w));
  u16* r16 = (u16*)S + (long)rid*2048;
  ((ushort4*)r16)[t] = hv;
  ((ushort4*)(r16 + 1024))[t] = lv;
}

__global__ void zero_k(int* __restrict__ counts, float* __restrict__ wG){
  int i = blockIdx.x*blockDim.x + threadIdx.x;
  if (i < 8) counts[i] = 0;
  for (int j = i; j < MAXSLOTS; j += gridDim.x*blockDim.x) wG[j] = 0.f;
}

__global__ __launch_bounds__(256)
void gating2_k(const float* __restrict__ x, const float* __restrict__ gnw,
               const float* __restrict__ gw, const int* __restrict__ tcnt,
               int* __restrict__ topi, float* __restrict__ topw,
               int* __restrict__ wPos, int* __restrict__ counts,
               int* __restrict__ sidx){
  const int t = threadIdx.x, lane = t & 63, w = t >> 6;
  const int n = blockIdx.x*4 + w;
  const int b = n >> 10, l = n & 1023;
  if (l >= tcnt[b]) return;
  const float* xr = x + (long)n*Hc;
  float ss = 0.f, sc[8] = {0,0,0,0,0,0,0,0};
  for (int j = 0; j < 16; j++){
    int d = j*64 + lane;
    float xv = xr[d];
    ss += xv*xv;
    float xg = xv * gnw[d];
#pragma unroll
    for (int e = 0; e < 8; e++) sc[e] += xg * gw[e*Hc + d];
  }
  for (int o = 32; o; o >>= 1){
    ss += __shfl_xor(ss, o);
#pragma unroll
    for (int e = 0; e < 8; e++) sc[e] += __shfl_xor(sc[e], o);
  }
  float rs = rsqrtf(ss*(1.f/Hc) + EPSc);
  float m = -3.4e38f;
#pragma unroll
  for (int e = 0; e < 8; e++){ sc[e] *= rs; m = fmaxf(m, sc[e]); }
  float p[8], sum = 0.f;
#pragma unroll
  for (int e = 0; e < 8; e++){ p[e] = __expf(sc[e] - m); sum += p[e]; }
  float inv = 1.f/sum;
#pragma unroll
  for (int e = 0; e < 8; e++) p[e] *= inv;
  int i1 = 0; float v1 = p[0];
#pragma unroll
  for (int e = 1; e < 8; e++) if (p[e] > v1){ v1 = p[e]; i1 = e; }
  int i2 = -1; float v2 = -1.f;
#pragma unroll
  for (int e = 0; e < 8; e++) if (e != i1 && p[e] > v2){ v2 = p[e]; i2 = e; }
  if (lane == 0){
    float dn = v1 + v2 + 1e-20f;
    int p0 = atomicAdd(&counts[i1], 1);
    int p1 = atomicAdd(&counts[i2], 1);
    sidx[i1*NTOK + p0] = n;
    sidx[i2*NTOK + p1] = n;
    topi[2*n] = i1; topi[2*n + 1] = i2;
    wPos[2*n] = p0; wPos[2*n + 1] = p1;
    topw[2*n] = v1/dn; topw[2*n + 1] = v2/dn;
  }
}

__global__ void scan_k(const int* __restrict__ counts, int* __restrict__ offs){
  if (threadIdx.x == 0){
    int o = 0; offs[0] = 0;
    for (int e = 0; e < 8; e++){ o += (counts[e] + 127) & ~127; offs[e+1] = o; }
  }
}

__global__ void gpos_k(const int* __restrict__ tcnt, const int* __restrict__ topi,
                       const int* __restrict__ wPos, const float* __restrict__ topw,
                       const int* __restrict__ offs, int* __restrict__ gpos,
                       float* __restrict__ wG){
  int n = blockIdx.x*blockDim.x + threadIdx.x;
  if (n >= NTOK) return;
  int b = n >> 10, l = n & 1023;
  if (l >= tcnt[b]){ gpos[2*n] = 0; gpos[2*n+1] = 0; return; }
  int g0 = offs[topi[2*n]]   + wPos[2*n];
  int g1 = offs[topi[2*n+1]] + wPos[2*n+1];
  gpos[2*n] = g0; gpos[2*n+1] = g1;
  wG[g0] = topw[2*n]; wG[g1] = topw[2*n+1];
}

__global__ void act_shared_k(const u16* __restrict__ gu, u16* __restrict__ z, long n){
  long i = (long)blockIdx.x*blockDim.x + threadIdx.x;
  long st = (long)gridDim.x*blockDim.x;
  for (; i < n; i += st){
    long nn = i >> 9;
    int  ii = (int)(i & (ISc - 1));
    float gv = bf2f(gu[nn*1024 + ii]);
    float uv = bf2f(gu[nn*1024 + ISc + ii]);
    z[i] = f2bf(gv/(1.f + __expf(-gv)) * uv);
  }
}

__global__ void act_slots_k(const u16* __restrict__ gu, const float* __restrict__ wG,
                            const int* __restrict__ offs, u16* __restrict__ z){
  long nmax = (long)offs[8]*256;
  long st = (long)gridDim.x*blockDim.x;
  for (long i = (long)blockIdx.x*blockDim.x + threadIdx.x; i < nmax; i += st){
    long s = i >> 8;
    int ii = (int)(i & 255);
    float gv = bf2f(gu[s*512 + ii]);
    float uv = bf2f(gu[s*512 + 256 + ii]);
    z[i] = f2bf(gv/(1.f + __expf(-gv)) * uv * wG[s]);
  }
}

__global__ void act_expert_k(const u16* __restrict__ gu, const int* __restrict__ topi,
                             const float* __restrict__ topw, int e,
                             u16* __restrict__ z, long n){
  long i = (long)blockIdx.x*blockDim.x + threadIdx.x;
  long st = (long)gridDim.x*blockDim.x;
  for (; i < n; i += st){
    long nn = i >> 8;
    int  ii = (int)(i & (Ic - 1));
    float wv = 0.f;
    if      (topi[2*nn]     == e) wv = topw[2*nn];
    else if (topi[2*nn + 1] == e) wv = topw[2*nn + 1];
    float gv = bf2f(gu[nn*512 + ii]);
    float uv = bf2f(gu[nn*512 + Ic + ii]);
    z[i] = f2bf(gv/(1.f + __expf(-gv)) * uv * wv);
  }
}

__global__ __launch_bounds__(256)
void final2_k(const float* __restrict__ ysh, const u16* __restrict__ D,
              const int* __restrict__ gpos, const float* __restrict__ ogw,
              const float* __restrict__ ogb, const int* __restrict__ cnt,
              float* __restrict__ out){
  const int t = threadIdx.x, lane = t & 63, w = t >> 6;
  const int n = blockIdx.x*4 + w;
  const int b = n >> 10, l = n & 1023;
  float* outr = out + (long)n*Hc;
  if (l >= cnt[b]){
#pragma unroll
    for (int j = 0; j < 16; j++) outr[j*64 + lane] = 0.f;
    return;
  }
  const float* yr = ysh + (long)n*Hc;
  const u16* d0 = D + (long)gpos[2*n]*1024;
  const u16* d1 = D + (long)gpos[2*n+1]*1024;
  float dot = 0.f, yv[16];
#pragma unroll
  for (int j = 0; j < 16; j++){
    int d = j*64 + lane;
    yv[j] = yr[d] + bf2f(d0[d]) + bf2f(d1[d]);
    dot += yv[j]*ogw[d];
  }
  for (int o = 32; o; o >>= 1) dot += __shfl_xor(dot, o);
  float s = 1.f/(1.f + __expf(-(dot + ogb[0])));
#pragma unroll
  for (int j = 0; j < 16; j++) outr[j*64 + lane] = yv[j]*s;
}

__global__ __launch_bounds__(256)
void final_k(const float* __restrict__ y, const float* __restrict__ ogw,
             const float* __restrict__ ogb, const int* __restrict__ cnt,
             float* __restrict__ out){
  const int t = threadIdx.x, lane = t & 63, w = t >> 6;
  const int n = blockIdx.x*4 + w;
  const int b = n >> 10, l = n & 1023;
  const bool pad = l >= cnt[b];
  const float* yr = y + (long)n*Hc;
  float dot = 0.f, yv[16];
#pragma unroll
  for (int j = 0; j < 16; j++){
    int d = j*64 + lane;
    yv[j] = yr[d];
    dot += yv[j]*ogw[d];
  }
  for (int o = 32; o; o >>= 1) dot += __shfl_xor(dot, o);
  float s = 1.f/(1.f + __expf(-(dot + ogb[0])));
  float* outr = out + (long)n*Hc;
#pragma unroll
  for (int j = 0; j < 16; j++){
    int d = j*64 + lane;
    outr[d] = pad ? 0.f : yv[j]*s;
  }
}

__global__ void sentinel_k(float* out){ out[0] = 1.0e9f; }

// ---------------------------------------------------------------------------
extern "C" void kernel_launch(void* const* d_in, const int* in_sizes, int n_in,
                              void* d_out, int out_size, void* d_ws, size_t ws_size,
                              hipStream_t stream){
  const float* hidden  = (const float*)d_in[0];
  const int*   cnt     = (const int*)  d_in[1];
  const float* ctx_nw  = (const float*)d_in[2];
  const float* Wqkv    = (const float*)d_in[3];
  const float* in_b    = (const float*)d_in[4];
  const float* Woutp   = (const float*)d_in[5];
  const float* out_b   = (const float*)d_in[6];
  const float* gate_nw = (const float*)d_in[7];
  const float* gate_w  = (const float*)d_in[8];
  const float* exp_nw  = (const float*)d_in[9];
  const float* Weg     = (const float*)d_in[10];
  const float* Weu     = (const float*)d_in[11];
  const float* Wed     = (const float*)d_in[12];
  const float* sh_nw   = (const float*)d_in[13];
  const float* Wsg     = (const float*)d_in[14];
  const float* Wsu     = (const float*)d_in[15];
  const float* Wsd     = (const float*)d_in[16];
  const float* ogw     = (const float*)d_in[17];
  const float* ogb     = (const float*)d_in[18];
  float* out = (float*)d_out;

  const size_t MB = 1024*1024;
  char* ws = (char*)d_ws;
  size_t off = 0;
  auto alloc = [&](size_t bytes)->char*{
    char* p = ws + off; off += (bytes + 255) & ~(size_t)255; return p;
  };
  u16* wWqH  = (u16*)alloc((size_t)3072*1024*2);
  u16* wWqL  = (u16*)alloc((size_t)3072*1024*2);
  u16* wWoH  = (u16*)alloc((size_t)1024*1024*2);
  u16* wWoL  = (u16*)alloc((size_t)1024*1024*2);
  u16* wWgu  = (u16*)alloc((size_t)Ec*2*Ic*Hc*2);
  u16* wWd   = (u16*)alloc((size_t)Ec*Hc*Ic*2);
  u16* wWsgu = (u16*)alloc((size_t)2*ISc*Hc*2);
  u16* wWsd  = (u16*)alloc((size_t)Hc*ISc*2);
  int*   wTopI = (int*)  alloc((size_t)NTOK*2*4);
  float* wTopW = (float*)alloc((size_t)NTOK*2*4);
  int*   wPos  = (int*)  alloc((size_t)NTOK*2*4);
  int*   wGpos = (int*)  alloc((size_t)NTOK*2*4);
  int*   wSidx = (int*)  alloc((size_t)Ec*NTOK*4);
  float* wG    = (float*)alloc((size_t)MAXSLOTS*4);
  int*   wCnts = (int*)  alloc(64);
  int*   wOffs = (int*)  alloc(64);
  char* P1 = alloc(32*MB);
  char* P2 = alloc(32*MB);
  char* P3 = alloc(32*MB);
  char* P4 = alloc(32*MB);
  size_t fixed = off;
  const bool big = (fixed + 64*MB) <= ws_size;
  char* P5 = alloc(big ? 64*MB : 16*MB);
  if (off > ws_size){ sentinel_k<<<1,1,0,stream>>>(out); return; }

  u16*   wNx   = (u16*)P1;
  u16*   wCtx  = (u16*)P1;
  float* wY    = (float*)P1;
  u16*   wQp   = (u16*)P2;
  u16*   wXhat = (u16*)P2;
  u16*   wSx   = (u16*)(P2 + 16*MB);
  u16*   wKp   = (u16*)P3;
  float* wX    = (float*)P3;
  u16*   wGUg  = (u16*)P3;
  u16*   wZg   = (u16*)(P3 + 18*MB);
  u16*   wGUe  = (u16*)P3;
  u16*   wZe   = (u16*)(P3 + 8*MB);
  u16*   wVtp  = (u16*)P4;
  u16*   wGUs  = (u16*)P4;
  u16*   wZs   = (u16*)(P4 + 16*MB);
  float* wS    = (float*)P5;
  u16*   wD    = (u16*)P5;

  // 1) weight prep
  split_cast_k<<<4096, 256, 0, stream>>>(Wqkv,  wWqH, wWqL, (long)3072*1024);
  split_cast_k<<<2048, 256, 0, stream>>>(Woutp, wWoH, wWoL, (long)1024*1024);
  cast_bf16_k<<<2048, 256, 0, stream>>>(Wed, wWd, (long)Ec*Hc*Ic);
  cast_bf16_k<<<1024, 256, 0, stream>>>(Wsg, wWsgu,                (long)ISc*Hc);
  cast_bf16_k<<<1024, 256, 0, stream>>>(Wsu, wWsgu + (long)ISc*Hc, (long)ISc*Hc);
  cast_bf16_k<<<1024, 256, 0, stream>>>(Wsd, wWsd, (long)Hc*ISc);
  fold_expert_k<<<2048, 256, 0, stream>>>(Weg, Weu, exp_nw, wWgu, (long)Ec*Ic*Hc);

  // 2) pre-attn norm + Q&K merged projection + V projection (pad-row skip, m-XCD grid)
  rmsnorm_split_k<<<NTOK, 256, 0, stream>>>(hidden, ctx_nw, wNx);
  if (big){
    gemm3<0, 1, 3, 2><<<dim3(64, 8, 2), 256, 0, stream>>>(
        wNx, wNx + 1024, wWqH, wWqL, wQp, in_b, nullptr,
        NTOK, 1024, 1024, 2048, 1024, 2048,
        0, 0, (long)1024*1024, 0, (long)16*1024*1024, 0,
        1024, 1024, cnt, 0);
    gemm3<3, 1, 3, 2><<<dim3(64, 8, 1), 256, 0, stream>>>(
        wNx, wNx + 1024, wWqH + (long)2048*1024, wWqL + (long)2048*1024, wVtp,
        in_b + 2048, nullptr, NTOK, 1024, 1024, 2048, 1024, 0,
        0, 0, 0, 0, 0, 0, 0, 0, cnt, 0);
  } else {
    gemm3<0, 1, 0, 0><<<dim3(8, 64, 2), 256, 0, stream>>>(
        wNx, wNx + 1024, wWqH, wWqL, wQp, in_b, nullptr,
        NTOK, 1024, 1024, 2048, 1024, 2048,
        0, 0, (long)1024*1024, 0, (long)16*1024*1024, 0,
        1024, 1024, nullptr, 0);
    gemm3<3, 1, 0, 0><<<dim3(8, 64, 1), 256, 0, stream>>>(
        wNx, wNx + 1024, wWqH + (long)2048*1024, wWqL + (long)2048*1024, wVtp,
        in_b + 2048, nullptr, NTOK, 1024, 1024, 2048, 1024, 0,
        0, 0, 0, 0, 0, 0, 0, 0, nullptr, 0);
  }

  // 3) attention
  if (big){
    for (int g = 0; g < 2; g++){
      const int bbase = g*4;
      const long tokoff = (long)g*4*Lc*2048;
      const u16* Qb = wQp + tokoff;
      const u16* Kb = wKp + tokoff;
      gemm3<1, 0, 1, 1><<<dim3(8, 8, 16), 256, 0, stream>>>(
          Qb, Qb + 1024, Kb, Kb + 1024, wS, nullptr, nullptr,
          Lc, Lc, HDc, 2048, 2048, Lc,
          (long)Lc*2048, (long)HDc,
          (long)Lc*2048, (long)HDc,
          (long)Lc*Lc,   (long)4*Lc*Lc,
          0, 0, cnt, bbase);
      softmax2_k<<<16*1024, 256, 0, stream>>>(wS, cnt, bbase);
      const u16* Vb = wVtp + (long)g*4*NHc*HDc*2048;
      u16* Cb = wCtx + tokoff;
      gemm3<0, 0, 2, 1><<<dim3(2, 8, 16), 256, 0, stream>>>(
          (const u16*)wS, (const u16*)wS + 1024, Vb, Vb + 1024, Cb, nullptr, nullptr,
          Lc, HDc, Lc, 2048, 2048, 2048,
          (long)Lc*2048,     (long)4*Lc*2048,
          (long)NHc*HDc*2048,(long)HDc*2048,
          (long)Lc*2048,     (long)HDc,
          1024, 0, cnt, bbase);
    }
  } else {
    for (int g = 0; g < 8; g++){
      const int hf = g >> 2, hbase = g & 3, bbase = hf*4;
      const long tokoff = (long)hf*4*Lc*2048;
      const u16* Qb = wQp + tokoff + hbase*HDc;
      const u16* Kb = wKp + tokoff + hbase*HDc;
      gemm3<1, 0, 1, 0><<<dim3(8, 8, 4), 256, 0, stream>>>(
          Qb, Qb + 1024, Kb, Kb + 1024, wS, nullptr, nullptr,
          Lc, Lc, HDc, 2048, 2048, Lc,
          (long)Lc*2048, (long)HDc,
          (long)Lc*2048, (long)HDc,
          (long)Lc*Lc,   (long)4*Lc*Lc,
          0, 0, cnt, bbase);
      softmax2_k<<<4*1024, 256, 0, stream>>>(wS, cnt, bbase);
      const u16* Vb = wVtp + (long)hf*4*NHc*HDc*2048 + (long)hbase*HDc*2048;
      u16* Cb = wCtx + tokoff + hbase*HDc;
      gemm3<0, 0, 2, 0><<<dim3(2, 8, 4), 256, 0, stream>>>(
          (const u16*)wS, (const u16*)wS + 1024, Vb, Vb + 1024, Cb, nullptr, nullptr,
          Lc, HDc, Lc, 2048, 2048, 2048,
          (long)Lc*2048,     (long)4*Lc*2048,
          (long)NHc*HDc*2048,(long)HDc*2048,
          (long)Lc*2048,     (long)HDc,
          1024, 0, cnt, bbase);
    }
  }

  // 4) out-proj + bias + residual -> X f32 (pad-row skip, m-XCD grid)
  if (big){
    gemm3<2, 1, 3, 2><<<dim3(64, 8, 1), 256, 0, stream>>>(
        wCtx, wCtx + 1024, wWoH, wWoL, wX, out_b, hidden,
        NTOK, 1024, 1024, 2048, 1024, 1024,
        0, 0, 0, 0, 0, 0, 0, 0, cnt, 0);
  } else {
    gemm3<2, 1, 0, 0><<<dim3(8, 64, 1), 256, 0, stream>>>(
        wCtx, wCtx + 1024, wWoH, wWoL, wX, out_b, hidden,
        NTOK, 1024, 1024, 2048, 1024, 1024,
        0, 0, 0, 0, 0, 0, 0, 0, nullptr, 0);
  }

  // 5) gating + post-norms
  zero_k<<<68, 256, 0, stream>>>(wCnts, wG);
  gating2_k<<<NTOK/4, 256, 0, stream>>>(wX, gate_nw, gate_w, cnt,
                                        wTopI, wTopW, wPos, wCnts, wSidx);
  scan_k<<<1, 64, 0, stream>>>(wCnts, wOffs);
  gpos_k<<<NTOK/256, 256, 0, stream>>>(cnt, wTopI, wPos, wTopW, wOffs, wGpos, wG);
  rmsnorm_k<<<NTOK, 256, 0, stream>>>(wX, wXhat, sh_nw, wSx);

  // 6) shared experts -> Y (pad-row skip, m-XCD grid)
  if (big){
    gemm_bt<0, 3, 2><<<dim3(64, 8, 1), 256, 0, stream>>>(
        wSx, wWsgu, wGUs, NTOK, 2*ISc, 1024, 1024, 1024, 2*ISc, 0, 0, 0, cnt);
    act_shared_k<<<4096, 256, 0, stream>>>(wGUs, wZs, (long)NTOK*ISc);
    gemm_bt<1, 3, 2><<<dim3(64, 8, 1), 256, 0, stream>>>(
        wZs, wWsd, wY, NTOK, 1024, ISc, ISc, ISc, 1024, 0, 0, 0, cnt);
  } else {
    gemm_bt<0, 0, 0><<<dim3(8, 64, 1), 256, 0, stream>>>(
        wSx, wWsgu, wGUs, NTOK, 2*ISc, 1024, 1024, 1024, 2*ISc, 0, 0, 0, nullptr);
    act_shared_k<<<4096, 256, 0, stream>>>(wGUs, wZs, (long)NTOK*ISc);
    gemm_bt<1, 0, 0><<<dim3(8, 64, 1), 256, 0, stream>>>(
        wZs, wWsd, wY, NTOK, 1024, ISc, ISc, ISc, 1024, 0, 0, 0, nullptr);
  }

  // 7) routed experts
  if (big){
    gemm_gu_gather<<<dim3(4, 64, Ec), 256, 0, stream>>>(
        wXhat, wWgu, wGUg, wSidx, wCnts, wOffs);
    act_slots_k<<<2048, 256, 0, stream>>>(wGUg, wG, wOffs, wZg);
    gemm_down_slots<<<dim3(8, MAXSLOTS/128, 1), 256, 0, stream>>>(
        wZg, wWd, wD, wOffs);
    final2_k<<<NTOK/4, 256, 0, stream>>>(wY, wD, wGpos, ogw, ogb, cnt, out);
  } else {
    for (int e = 0; e < Ec; e++){
      gemm_bt<0, 0, 0><<<dim3(4, 64, 1), 256, 0, stream>>>(
          wXhat, wWgu + (long)e*2*Ic*Hc, wGUe, NTOK, 2*Ic, 1024, 1024, 1024, 2*Ic,
          0, 0, 0, nullptr);
      act_expert_k<<<2048, 256, 0, stream>>>(wGUe, wTopI, wTopW, e, wZe, (long)NTOK*Ic);
      gemm_bt<2, 0, 0><<<dim3(8, 64, 1), 256, 0, stream>>>(
          wZe, wWd + (long)e*Hc*Ic, wY, NTOK, 1024, Ic, Ic, Ic, 1024, 0, 0, 0, nullptr);
    }
    final_k<<<NTOK/4, 256, 0, stream>>>(wY, ogw, ogb, cnt, out);
  }
}

// Round 8
// 659.804 us; speedup vs baseline: 2.1298x; 1.1118x over previous
//
#include <hip/hip_runtime.h>
#include <hip/hip_bf16.h>

typedef unsigned short u16;
typedef unsigned int   u32;
typedef short bf16x8 __attribute__((ext_vector_type(8)));
typedef float f32x4  __attribute__((ext_vector_type(4)));

#define DEV static __device__ __forceinline__

#define Bc 8
#define Lc 1024
#define Hc 1024
#define Ec 8
#define Ic 256
#define ISc 512
#define NHc 4
#define HDc 256
#define NTOK 8192
#define EPSc 1e-6f
#define MAXSLOTS 17408

DEV u16 f2bf(float f){
  u32 u = __float_as_uint(f);
  return (u16)((u + 0x7fffu + ((u >> 16) & 1u)) >> 16);
}
DEV float bf2f(u16 h){ return __uint_as_float(((u32)h) << 16); }

DEV void gload_lds16(const void* g, void* l){
  __builtin_amdgcn_global_load_lds((const __attribute__((address_space(1))) u32*)g,
                                   (__attribute__((address_space(3))) u32*)l, 16, 0, 0);
}

// ---------------------------------------------------------------------------
// Split-precision NT GEMM: C = (Ahi+Alo)·(Bhi+Blo)^T ≈ AhiBhi + AhiBlo + AloBhi
// EPI: 0 = packed hi|lo store (lo at +loOffC), 1 = f32, 2 = f32 acc+bias+Res,
//      3 = V-transpose packed hi|lo
// SKIP: 0 none; 1 = attn QK: skip if m0>=tc[b] or n0>=tc[b]
//       2 = attn PV: skip if m0>=tc[b], clamp K to ceil32(tc[b])
//       3 = token rows (M=8192): skip if (m0&1023)>=tc[m0>>10]
// SWZ:  0 default (x=n,y=m); 1 = slice->XCD swizzle (gridDim.z==16);
//       2 = transposed grid (x=m,y=n) -> A-panel per XCD
// ---------------------------------------------------------------------------
template<int EPI, int BIAS, int SKIP, int SWZ>
__global__ __launch_bounds__(256)
void gemm3(const u16* __restrict__ Ahi, const u16* __restrict__ Alo,
           const u16* __restrict__ Bhi, const u16* __restrict__ Blo,
           void* __restrict__ Cv, const float* __restrict__ bias,
           const float* __restrict__ Res,
           int M, int N, int K, int lda, int ldb, int ldc,
           long sAin, long sAout, long sBin, long sBout, long sCin, long sCout,
           int loOffC, int biasStride, const int* __restrict__ tc, int bbase)
{
  __shared__ u16 lsAh[128*32];
  __shared__ u16 lsAl[128*32];
  __shared__ u16 lsBh[128*32];
  __shared__ u16 lsBl[128*32];
  int m_i, n_i, z;
  if (SWZ == 1){
    const int NB = gridDim.x*gridDim.y;
    const int L = blockIdx.x + gridDim.x*(blockIdx.y + gridDim.y*blockIdx.z);
    const int r = L & 7, k = L >> 3;
    z = r + 8*(k / NB);
    const int idx = k % NB;
    n_i = idx % gridDim.x; m_i = idx / gridDim.x;
  } else if (SWZ == 2){
    m_i = blockIdx.x; n_i = blockIdx.y; z = blockIdx.z;
  } else {
    n_i = blockIdx.x; m_i = blockIdx.y; z = blockIdx.z;
  }
  const int n0 = n_i*128, m0 = m_i*128;
  const int zin = z & 3, zout = z >> 2;
  if (SKIP == 1){ const int c = tc[bbase + zin]; if (m0 >= c || n0 >= c) return; }
  if (SKIP == 2){ const int c = tc[bbase + zin]; if (m0 >= c) return;
                  const int kl = (c + 31) & ~31; K = K < kl ? K : kl; }
  if (SKIP == 3){ if ((m0 & 1023) >= tc[m0 >> 10]) return; }
  const long aoff = (long)zin*sAin + (long)zout*sAout;
  const long boff = (long)zin*sBin + (long)zout*sBout;
  const long coff = (long)zin*sCin + (long)zout*sCout;
  const u16* Ahb = Ahi + aoff;
  const u16* Alb = Alo + aoff;
  const u16* Bhb = Bhi + boff;
  const u16* Blb = Blo + boff;
  const int t = threadIdx.x, lane = t & 63;
  const int w = t >> 6, wm = w >> 1, wn = w & 1;
  const int fr = lane & 15, kg = lane >> 4;
  const int srow = t >> 2, scol = (t & 3) * 8;
  f32x4 acc[4][4] = {};

  for (int kb = 0; kb < K; kb += 32){
    gload_lds16(Ahb + (long)(m0 +      srow)*lda + kb + scol, &lsAh[srow*32 + scol]);
    gload_lds16(Ahb + (long)(m0 + 64 + srow)*lda + kb + scol, &lsAh[(64+srow)*32 + scol]);
    gload_lds16(Alb + (long)(m0 +      srow)*lda + kb + scol, &lsAl[srow*32 + scol]);
    gload_lds16(Alb + (long)(m0 + 64 + srow)*lda + kb + scol, &lsAl[(64+srow)*32 + scol]);
    gload_lds16(Bhb + (long)(n0 +      srow)*ldb + kb + scol, &lsBh[srow*32 + scol]);
    gload_lds16(Bhb + (long)(n0 + 64 + srow)*ldb + kb + scol, &lsBh[(64+srow)*32 + scol]);
    gload_lds16(Blb + (long)(n0 +      srow)*ldb + kb + scol, &lsBl[srow*32 + scol]);
    gload_lds16(Blb + (long)(n0 + 64 + srow)*ldb + kb + scol, &lsBl[(64+srow)*32 + scol]);
    asm volatile("s_waitcnt vmcnt(0)" ::: "memory");
    __syncthreads();
    bf16x8 ah[4], al[4], bh[4], bl[4];
#pragma unroll
    for (int i = 0; i < 4; i++){
      ah[i] = *(const bf16x8*)&lsAh[(wm*64 + i*16 + fr)*32 + kg*8];
      al[i] = *(const bf16x8*)&lsAl[(wm*64 + i*16 + fr)*32 + kg*8];
      bh[i] = *(const bf16x8*)&lsBh[(wn*64 + i*16 + fr)*32 + kg*8];
      bl[i] = *(const bf16x8*)&lsBl[(wn*64 + i*16 + fr)*32 + kg*8];
    }
#pragma unroll
    for (int mi = 0; mi < 4; mi++)
#pragma unroll
      for (int ni = 0; ni < 4; ni++){
        acc[mi][ni] = __builtin_amdgcn_mfma_f32_16x16x32_bf16(ah[mi], bh[ni], acc[mi][ni], 0, 0, 0);
        acc[mi][ni] = __builtin_amdgcn_mfma_f32_16x16x32_bf16(ah[mi], bl[ni], acc[mi][ni], 0, 0, 0);
        acc[mi][ni] = __builtin_amdgcn_mfma_f32_16x16x32_bf16(al[mi], bh[ni], acc[mi][ni], 0, 0, 0);
      }
    __syncthreads();
  }

  const int r4 = (lane >> 4) * 4;
#pragma unroll
  for (int mi = 0; mi < 4; mi++){
#pragma unroll
    for (int ni = 0; ni < 4; ni++){
      const int col = n0 + wn*64 + ni*16 + fr;
      const float bb = BIAS ? bias[zin*biasStride + col] : 0.f;
#pragma unroll
      for (int r = 0; r < 4; r++){
        const int row = m0 + wm*64 + mi*16 + r4 + r;
        float v = acc[mi][ni][r] + bb;
        if (EPI == 0){
          u16 hv = f2bf(v), lv = f2bf(v - bf2f(hv));
          long idx = coff + (long)row*ldc + col;
          ((u16*)Cv)[idx] = hv;
          ((u16*)Cv)[idx + loOffC] = lv;
        } else if (EPI == 1){
          ((float*)Cv)[coff + (long)row*ldc + col] = v;
        } else if (EPI == 2){
          long idx = coff + (long)row*ldc + col;
          ((float*)Cv)[idx] = v + Res[idx];
        } else {
          u16 hv = f2bf(v), lv = f2bf(v - bf2f(hv));
          int b = row >> 10, q = row & 1023;
          int h = col >> 8, d = col & 255;
          long o = ((long)(b*NHc + h)*HDc + d)*2048 + q;
          ((u16*)Cv)[o] = hv;
          ((u16*)Cv)[o + 1024] = lv;
        }
      }
    }
  }
}

// ---------------------------------------------------------------------------
// Plain bf16 NT GEMM. EPI: 0 bf16, 1 f32, 2 f32 +=. SKIP 3 = pad-row skip.
// SWZ 2 = transposed grid (x=m,y=n).
template<int EPI, int SKIP, int SWZ>
__global__ __launch_bounds__(256)
void gemm_bt(const u16* __restrict__ A, const u16* __restrict__ B,
             void* __restrict__ Cv,
             int M, int N, int K, int lda, int ldb, int ldc,
             long sAz, long sBz, long sCz, const int* __restrict__ tc)
{
  __shared__ u16 lsA[128*32];
  __shared__ u16 lsB[128*32];
  int m_i, n_i;
  if (SWZ == 2){ m_i = blockIdx.x; n_i = blockIdx.y; }
  else         { n_i = blockIdx.x; m_i = blockIdx.y; }
  const int z = blockIdx.z;
  const int n0 = n_i*128, m0 = m_i*128;
  if (SKIP == 3){ if ((m0 & 1023) >= tc[m0 >> 10]) return; }
  const u16* Ab = A + (long)z*sAz;
  const u16* Bb = B + (long)z*sBz;
  const int t = threadIdx.x, lane = t & 63;
  const int w = t >> 6, wm = w >> 1, wn = w & 1;
  const int fr = lane & 15, kg = lane >> 4;
  const int srow = t >> 2, scol = (t & 3) * 8;
  f32x4 acc[4][4] = {};

  for (int kb = 0; kb < K; kb += 32){
    gload_lds16(Ab + (long)(m0 +      srow)*lda + kb + scol, &lsA[srow*32 + scol]);
    gload_lds16(Ab + (long)(m0 + 64 + srow)*lda + kb + scol, &lsA[(64+srow)*32 + scol]);
    gload_lds16(Bb + (long)(n0 +      srow)*ldb + kb + scol, &lsB[srow*32 + scol]);
    gload_lds16(Bb + (long)(n0 + 64 + srow)*ldb + kb + scol, &lsB[(64+srow)*32 + scol]);
    asm volatile("s_waitcnt vmcnt(0)" ::: "memory");
    __syncthreads();
    bf16x8 av[4], bv[4];
#pragma unroll
    for (int i = 0; i < 4; i++){
      av[i] = *(const bf16x8*)&lsA[(wm*64 + i*16 + fr)*32 + kg*8];
      bv[i] = *(const bf16x8*)&lsB[(wn*64 + i*16 + fr)*32 + kg*8];
    }
#pragma unroll
    for (int mi = 0; mi < 4; mi++)
#pragma unroll
      for (int ni = 0; ni < 4; ni++)
        acc[mi][ni] = __builtin_amdgcn_mfma_f32_16x16x32_bf16(av[mi], bv[ni], acc[mi][ni], 0, 0, 0);
    __syncthreads();
  }

  const int r4 = (lane >> 4) * 4;
#pragma unroll
  for (int mi = 0; mi < 4; mi++){
#pragma unroll
    for (int ni = 0; ni < 4; ni++){
      const int col = n0 + wn*64 + ni*16 + fr;
#pragma unroll
      for (int r = 0; r < 4; r++){
        const int row = m0 + wm*64 + mi*16 + r4 + r;
        const long idx = (long)z*sCz + (long)row*ldc + col;
        float v = acc[mi][ni][r];
        if      (EPI == 0) ((u16*)Cv)[idx]   = f2bf(v);
        else if (EPI == 1) ((float*)Cv)[idx] = v;
        else               ((float*)Cv)[idx] += v;
      }
    }
  }
}

// ---------------------------------------------------------------------------
// Gathered GU GEMM: per expert e, rows = tokens from sidx
__global__ __launch_bounds__(256)
void gemm_gu_gather(const u16* __restrict__ A, const u16* __restrict__ Ball,
                    u16* __restrict__ Cg, const int* __restrict__ sidx,
                    const int* __restrict__ counts, const int* __restrict__ offs)
{
  __shared__ u16 lsA[128*32];
  __shared__ u16 lsB[128*32];
  const int e = blockIdx.z;
  const int cnt = counts[e];
  const int obase = offs[e];
  const int padc = offs[e+1] - obase;
  const int m0 = blockIdx.y*128;
  if (m0 >= padc) return;
  const int n0 = blockIdx.x*128;
  const u16* B = Ball + (long)e*512*1024;
  const int t = threadIdx.x, lane = t & 63;
  const int w = t >> 6, wm = w >> 1, wn = w & 1;
  const int fr = lane & 15, kg = lane >> 4;
  const int srow = t >> 2, scol = (t & 3) * 8;
  const int s0 = m0 + srow, s1 = m0 + 64 + srow;
  const int tok0 = (s0 < cnt) ? sidx[e*NTOK + s0] : 0;
  const int tok1 = (s1 < cnt) ? sidx[e*NTOK + s1] : 0;
  f32x4 acc[4][4] = {};

  for (int kb = 0; kb < 1024; kb += 32){
    gload_lds16(A + (long)tok0*1024 + kb + scol, &lsA[srow*32 + scol]);
    gload_lds16(A + (long)tok1*1024 + kb + scol, &lsA[(64+srow)*32 + scol]);
    gload_lds16(B + (long)(n0 +      srow)*1024 + kb + scol, &lsB[srow*32 + scol]);
    gload_lds16(B + (long)(n0 + 64 + srow)*1024 + kb + scol, &lsB[(64+srow)*32 + scol]);
    asm volatile("s_waitcnt vmcnt(0)" ::: "memory");
    __syncthreads();
    bf16x8 av[4], bv[4];
#pragma unroll
    for (int i = 0; i < 4; i++){
      av[i] = *(const bf16x8*)&lsA[(wm*64 + i*16 + fr)*32 + kg*8];
      bv[i] = *(const bf16x8*)&lsB[(wn*64 + i*16 + fr)*32 + kg*8];
    }
#pragma unroll
    for (int mi = 0; mi < 4; mi++)
#pragma unroll
      for (int ni = 0; ni < 4; ni++)
        acc[mi][ni] = __builtin_amdgcn_mfma_f32_16x16x32_bf16(av[mi], bv[ni], acc[mi][ni], 0, 0, 0);
    __syncthreads();
  }

  const int r4 = (lane >> 4) * 4;
#pragma unroll
  for (int mi = 0; mi < 4; mi++){
#pragma unroll
    for (int ni = 0; ni < 4; ni++){
      const int col = wn*64 + ni*16 + fr + n0;
#pragma unroll
      for (int r = 0; r < 4; r++){
        const int row = m0 + wm*64 + mi*16 + r4 + r;
        Cg[(long)(obase + row)*512 + col] = f2bf(acc[mi][ni][r]);
      }
    }
  }
}

// Down GEMM dense over slot space
__global__ __launch_bounds__(256)
void gemm_down_slots(const u16* __restrict__ Zg, const u16* __restrict__ Wd,
                     u16* __restrict__ D, const int* __restrict__ offs)
{
  __shared__ u16 lsA[128*32];
  __shared__ u16 lsB[128*32];
  const int m0 = blockIdx.y*128;
  if (m0 >= offs[8]) return;
  int e = 0;
#pragma unroll
  for (int i = 0; i < 7; i++) if (m0 >= offs[i+1]) e = i+1;
  const u16* B = Wd + (long)e*1024*256;
  const int n0 = blockIdx.x*128;
  const int t = threadIdx.x, lane = t & 63;
  const int w = t >> 6, wm = w >> 1, wn = w & 1;
  const int fr = lane & 15, kg = lane >> 4;
  const int srow = t >> 2, scol = (t & 3) * 8;
  f32x4 acc[4][4] = {};

  for (int kb = 0; kb < 256; kb += 32){
    gload_lds16(Zg + (long)(m0 +      srow)*256 + kb + scol, &lsA[srow*32 + scol]);
    gload_lds16(Zg + (long)(m0 + 64 + srow)*256 + kb + scol, &lsA[(64+srow)*32 + scol]);
    gload_lds16(B  + (long)(n0 +      srow)*256 + kb + scol, &lsB[srow*32 + scol]);
    gload_lds16(B  + (long)(n0 + 64 + srow)*256 + kb + scol, &lsB[(64+srow)*32 + scol]);
    asm volatile("s_waitcnt vmcnt(0)" ::: "memory");
    __syncthreads();
    bf16x8 av[4], bv[4];
#pragma unroll
    for (int i = 0; i < 4; i++){
      av[i] = *(const bf16x8*)&lsA[(wm*64 + i*16 + fr)*32 + kg*8];
      bv[i] = *(const bf16x8*)&lsB[(wn*64 + i*16 + fr)*32 + kg*8];
    }
#pragma unroll
    for (int mi = 0; mi < 4; mi++)
#pragma unroll
      for (int ni = 0; ni < 4; ni++)
        acc[mi][ni] = __builtin_amdgcn_mfma_f32_16x16x32_bf16(av[mi], bv[ni], acc[mi][ni], 0, 0, 0);
    __syncthreads();
  }

  const int r4 = (lane >> 4) * 4;
#pragma unroll
  for (int mi = 0; mi < 4; mi++){
#pragma unroll
    for (int ni = 0; ni < 4; ni++){
      const int col = n0 + wn*64 + ni*16 + fr;
#pragma unroll
      for (int r = 0; r < 4; r++){
        const int row = m0 + wm*64 + mi*16 + r4 + r;
        D[(long)row*1024 + col] = f2bf(acc[mi][ni][r]);
      }
    }
  }
}

// ---------------------------------------------------------------------------
__global__ void cast_bf16_k(const float* __restrict__ in, u16* __restrict__ out, long n){
  long i = (long)blockIdx.x*blockDim.x + threadIdx.x;
  long st = (long)gridDim.x*blockDim.x;
  for (; i < n; i += st) out[i] = f2bf(in[i]);
}

__global__ void split_cast_k(const float* __restrict__ in, u16* __restrict__ hi,
                             u16* __restrict__ lo, long n){
  long i = (long)blockIdx.x*blockDim.x + threadIdx.x;
  long st = (long)gridDim.x*blockDim.x;
  for (; i < n; i += st){
    float v = in[i];
    u16 h = f2bf(v);
    hi[i] = h;
    lo[i] = f2bf(v - bf2f(h));
  }
}

__global__ void fold_expert_k(const float* __restrict__ g, const float* __restrict__ u,
                              const float* __restrict__ nw, u16* __restrict__ gu, long n){
  long i = (long)blockIdx.x*blockDim.x + threadIdx.x;
  long st = (long)gridDim.x*blockDim.x;
  for (; i < n; i += st){
    int h  = (int)(i & (Hc - 1));
    int ii = (int)((i >> 10) & (Ic - 1));
    int e  = (int)(i >> 18);
    float wv = nw[e*Hc + h];
    long o = (long)e*(2*Ic*Hc) + (long)ii*Hc + h;
    gu[o]         = f2bf(g[i]*wv);
    gu[o + Ic*Hc] = f2bf(u[i]*wv);
  }
}

__global__ __launch_bounds__(256)
void rmsnorm_split_k(const float* __restrict__ x, const float* __restrict__ w1,
                     u16* __restrict__ o){
  const int row = blockIdx.x, t = threadIdx.x, lane = t & 63, w = t >> 6;
  float4 v = ((const float4*)(x + (long)row*Hc))[t];
  float ss = v.x*v.x + v.y*v.y + v.z*v.z + v.w*v.w;
  for (int off = 32; off; off >>= 1) ss += __shfl_xor(ss, off);
  __shared__ float red[4];
  if (lane == 0) red[w] = ss;
  __syncthreads();
  float rs = rsqrtf((red[0]+red[1]+red[2]+red[3])*(1.f/Hc) + EPSc);
  float4 wv = ((const float4*)w1)[t];
  float f0 = v.x*rs*wv.x, f1 = v.y*rs*wv.y, f2 = v.z*rs*wv.z, f3 = v.w*rs*wv.w;
  ushort4 hv, lv;
  hv.x = f2bf(f0); lv.x = f2bf(f0 - bf2f(hv.x));
  hv.y = f2bf(f1); lv.y = f2bf(f1 - bf2f(hv.y));
  hv.z = f2bf(f2); lv.z = f2bf(f2 - bf2f(hv.z));
  hv.w = f2bf(f3); lv.w = f2bf(f3 - bf2f(hv.w));
  u16* r16 = o + (long)row*2048;
  ((ushort4*)r16)[t] = hv;
  ((ushort4*)(r16 + 1024))[t] = lv;
}

__global__ __launch_bounds__(256)
void rmsnorm_k(const float* __restrict__ x, u16* __restrict__ o1,
               const float* __restrict__ w2, u16* __restrict__ o2){
  const int row = blockIdx.x, t = threadIdx.x, lane = t & 63, w = t >> 6;
  float4 v = ((const float4*)(x + (long)row*Hc))[t];
  float ss = v.x*v.x + v.y*v.y + v.z*v.z + v.w*v.w;
  for (int off = 32; off; off >>= 1) ss += __shfl_xor(ss, off);
  __shared__ float red[4];
  if (lane == 0) red[w] = ss;
  __syncthreads();
  float rs = rsqrtf((red[0]+red[1]+red[2]+red[3])*(1.f/Hc) + EPSc);
  ushort4 ov;
  ov.x = f2bf(v.x*rs); ov.y = f2bf(v.y*rs); ov.z = f2bf(v.z*rs); ov.w = f2bf(v.w*rs);
  ((ushort4*)o1)[(long)row*256 + t] = ov;
  float4 wv = ((const float4*)w2)[t];
  ov.x = f2bf(v.x*rs*wv.x); ov.y = f2bf(v.y*rs*wv.y);
  ov.z = f2bf(v.z*rs*wv.z); ov.w = f2bf(v.w*rs*wv.w);
  ((ushort4*)o2)[(long)row*256 + t] = ov;
}

// masked softmax; skips padded q rows. slice = rid>>10, batch = bbase+(slice&3)
__global__ __launch_bounds__(256)
void softmax2_k(float* __restrict__ S, const int* __restrict__ cnt, int bbase){
  const int rid = blockIdx.x;
  const int b = bbase + ((rid >> 10) & 3);
  const int n = cnt[b];
  if ((rid & 1023) >= n) return;
  float* row = S + (long)rid*Lc;
  const int t = threadIdx.x, lane = t & 63, w = t >> 6;
  float4 v = ((const float4*)row)[t];
  const float sc = 0.0625f;
  float vals[4] = {v.x*sc, v.y*sc, v.z*sc, v.w*sc};
  const int c = t*4;
  float m = -3.4e38f;
#pragma unroll
  for (int j = 0; j < 4; j++) if (c + j < n) m = fmaxf(m, vals[j]);
  for (int o = 32; o; o >>= 1) m = fmaxf(m, __shfl_xor(m, o));
  __shared__ float red[8];
  if (lane == 0) red[w] = m;
  __syncthreads();
  m = fmaxf(fmaxf(red[0], red[1]), fmaxf(red[2], red[3]));
  float p[4], s = 0.f;
#pragma unroll
  for (int j = 0; j < 4; j++){ p[j] = (c + j < n) ? __expf(vals[j] - m) : 0.f; s += p[j]; }
  for (int o = 32; o; o >>= 1) s += __shfl_xor(s, o);
  if (lane == 0) red[4 + w] = s;
  __syncthreads();
  const float inv = 1.f / (red[4]+red[5]+red[6]+red[7]);
  ushort4 hv, lv;
  float q0 = p[0]*inv, q1 = p[1]*inv, q2 = p[2]*inv, q3 = p[3]*inv;
  hv.x = f2bf(q0); lv.x = f2bf(q0 - bf2f(hv.x));
  hv.y = f2bf(q1); lv.y = f2bf(q1 - bf2f(hv.y));
  hv.z = f2bf(q2); lv.z = f2bf(q2 - bf2f(hv.z));
  hv.w = f2bf(q3); lv.w = f2bf(q3 - bf2f(hv.w));
  u16* r16 = (u16*)S + (long)rid*2048;
  ((ushort4*)r16)[t] = hv;
  ((ushort4*)(r16 + 1024))[t] = lv;
}

// gating scores: one wave per token, f32; NO atomics — just top-2 per token
__global__ __launch_bounds__(256)
void gating_score_k(const float* __restrict__ x, const float* __restrict__ gnw,
                    const float* __restrict__ gw, const int* __restrict__ tcnt,
                    int* __restrict__ topi, float* __restrict__ topw){
  const int t = threadIdx.x, lane = t & 63, w = t >> 6;
  const int n = blockIdx.x*4 + w;
  const int b = n >> 10, l = n & 1023;
  if (l >= tcnt[b]) return;
  const float* xr = x + (long)n*Hc;
  float ss = 0.f, sc[8] = {0,0,0,0,0,0,0,0};
  for (int j = 0; j < 16; j++){
    int d = j*64 + lane;
    float xv = xr[d];
    ss += xv*xv;
    float xg = xv * gnw[d];
#pragma unroll
    for (int e = 0; e < 8; e++) sc[e] += xg * gw[e*Hc + d];
  }
  for (int o = 32; o; o >>= 1){
    ss += __shfl_xor(ss, o);
#pragma unroll
    for (int e = 0; e < 8; e++) sc[e] += __shfl_xor(sc[e], o);
  }
  float rs = rsqrtf(ss*(1.f/Hc) + EPSc);
  float m = -3.4e38f;
#pragma unroll
  for (int e = 0; e < 8; e++){ sc[e] *= rs; m = fmaxf(m, sc[e]); }
  float p[8], sum = 0.f;
#pragma unroll
  for (int e = 0; e < 8; e++){ p[e] = __expf(sc[e] - m); sum += p[e]; }
  float inv = 1.f/sum;
#pragma unroll
  for (int e = 0; e < 8; e++) p[e] *= inv;
  int i1 = 0; float v1 = p[0];
#pragma unroll
  for (int e = 1; e < 8; e++) if (p[e] > v1){ v1 = p[e]; i1 = e; }
  int i2 = -1; float v2 = -1.f;
#pragma unroll
  for (int e = 0; e < 8; e++) if (e != i1 && p[e] > v2){ v2 = p[e]; i2 = e; }
  if (lane == 0){
    float dn = v1 + v2 + 1e-20f;
    topi[2*n] = i1; topi[2*n + 1] = i2;
    topw[2*n] = v1/dn; topw[2*n + 1] = v2/dn;
  }
}

// deterministic routing build: single block, 1024 threads, token-ordered.
// Produces counts/offs/sidx/gpos/wG (wG zeroed here too).
__global__ __launch_bounds__(1024)
void route_scan_k(const int* __restrict__ tcnt, const int* __restrict__ topi,
                  const float* __restrict__ topw, int* __restrict__ counts,
                  int* __restrict__ offs, int* __restrict__ sidx,
                  int* __restrict__ gpos, float* __restrict__ wG){
  __shared__ int hist[1024][8];
  __shared__ int soffs[9];
  const int t = threadIdx.x;
  for (int i = t; i < MAXSLOTS; i += 1024) wG[i] = 0.f;
  int h[8] = {0,0,0,0,0,0,0,0};
  const int n0 = t*8;
  int e0[8], e1[8];
#pragma unroll
  for (int k = 0; k < 8; k++){
    const int n = n0 + k;
    const int b = n >> 10, l = n & 1023;
    const bool val = l < tcnt[b];
    e0[k] = val ? topi[2*n]   : -1;
    e1[k] = val ? topi[2*n+1] : -1;
    if (val){ h[e0[k]]++; h[e1[k]]++; }
  }
#pragma unroll
  for (int e = 0; e < 8; e++) hist[t][e] = h[e];
  __syncthreads();
  for (int off = 1; off < 1024; off <<= 1){
    int v[8];
#pragma unroll
    for (int e = 0; e < 8; e++)
      v[e] = hist[t][e] + ((t >= off) ? hist[t - off][e] : 0);
    __syncthreads();
#pragma unroll
    for (int e = 0; e < 8; e++) hist[t][e] = v[e];
    __syncthreads();
  }
  if (t == 0){
    int o = 0; soffs[0] = 0; offs[0] = 0;
    for (int e = 0; e < 8; e++){
      int c = hist[1023][e];
      counts[e] = c;
      o += (c + 127) & ~127;
      soffs[e+1] = o;
      offs[e+1] = o;
    }
  }
  __syncthreads();
  int run[8];
#pragma unroll
  for (int e = 0; e < 8; e++) run[e] = hist[t][e] - h[e];   // exclusive prefix
#pragma unroll
  for (int k = 0; k < 8; k++){
    const int n = n0 + k;
    if (e0[k] >= 0){
      const int p0 = run[e0[k]]++;
      const int p1 = run[e1[k]]++;
      sidx[e0[k]*NTOK + p0] = n;
      sidx[e1[k]*NTOK + p1] = n;
      const int g0 = soffs[e0[k]] + p0, g1 = soffs[e1[k]] + p1;
      gpos[2*n] = g0; gpos[2*n+1] = g1;
      wG[g0] = topw[2*n]; wG[g1] = topw[2*n+1];
    } else {
      gpos[2*n] = 0; gpos[2*n+1] = 0;
    }
  }
}

__global__ void act_shared_k(const u16* __restrict__ gu, u16* __restrict__ z, long n){
  long i = (long)blockIdx.x*blockDim.x + threadIdx.x;
  long st = (long)gridDim.x*blockDim.x;
  for (; i < n; i += st){
    long nn = i >> 9;
    int  ii = (int)(i & (ISc - 1));
    float gv = bf2f(gu[nn*1024 + ii]);
    float uv = bf2f(gu[nn*1024 + ISc + ii]);
    z[i] = f2bf(gv/(1.f + __expf(-gv)) * uv);
  }
}

__global__ void act_slots_k(const u16* __restrict__ gu, const float* __restrict__ wG,
                            const int* __restrict__ offs, u16* __restrict__ z){
  long nmax = (long)offs[8]*256;
  long st = (long)gridDim.x*blockDim.x;
  for (long i = (long)blockIdx.x*blockDim.x + threadIdx.x; i < nmax; i += st){
    long s = i >> 8;
    int ii = (int)(i & 255);
    float gv = bf2f(gu[s*512 + ii]);
    float uv = bf2f(gu[s*512 + 256 + ii]);
    z[i] = f2bf(gv/(1.f + __expf(-gv)) * uv * wG[s]);
  }
}

__global__ void act_expert_k(const u16* __restrict__ gu, const int* __restrict__ topi,
                             const float* __restrict__ topw, int e,
                             u16* __restrict__ z, long n){
  long i = (long)blockIdx.x*blockDim.x + threadIdx.x;
  long st = (long)gridDim.x*blockDim.x;
  for (; i < n; i += st){
    long nn = i >> 8;
    int  ii = (int)(i & (Ic - 1));
    float wv = 0.f;
    if      (topi[2*nn]     == e) wv = topw[2*nn];
    else if (topi[2*nn + 1] == e) wv = topw[2*nn + 1];
    float gv = bf2f(gu[nn*512 + ii]);
    float uv = bf2f(gu[nn*512 + Ic + ii]);
    z[i] = f2bf(gv/(1.f + __expf(-gv)) * uv * wv);
  }
}

__global__ __launch_bounds__(256)
void final2_k(const float* __restrict__ ysh, const u16* __restrict__ D,
              const int* __restrict__ gpos, const float* __restrict__ ogw,
              const float* __restrict__ ogb, const int* __restrict__ cnt,
              float* __restrict__ out){
  const int t = threadIdx.x, lane = t & 63, w = t >> 6;
  const int n = blockIdx.x*4 + w;
  const int b = n >> 10, l = n & 1023;
  float* outr = out + (long)n*Hc;
  if (l >= cnt[b]){
#pragma unroll
    for (int j = 0; j < 16; j++) outr[j*64 + lane] = 0.f;
    return;
  }
  const float* yr = ysh + (long)n*Hc;
  const u16* d0 = D + (long)gpos[2*n]*1024;
  const u16* d1 = D + (long)gpos[2*n+1]*1024;
  float dot = 0.f, yv[16];
#pragma unroll
  for (int j = 0; j < 16; j++){
    int d = j*64 + lane;
    yv[j] = yr[d] + bf2f(d0[d]) + bf2f(d1[d]);
    dot += yv[j]*ogw[d];
  }
  for (int o = 32; o; o >>= 1) dot += __shfl_xor(dot, o);
  float s = 1.f/(1.f + __expf(-(dot + ogb[0])));
#pragma unroll
  for (int j = 0; j < 16; j++) outr[j*64 + lane] = yv[j]*s;
}

__global__ __launch_bounds__(256)
void final_k(const float* __restrict__ y, const float* __restrict__ ogw,
             const float* __restrict__ ogb, const int* __restrict__ cnt,
             float* __restrict__ out){
  const int t = threadIdx.x, lane = t & 63, w = t >> 6;
  const int n = blockIdx.x*4 + w;
  const int b = n >> 10, l = n & 1023;
  const bool pad = l >= cnt[b];
  const float* yr = y + (long)n*Hc;
  float dot = 0.f, yv[16];
#pragma unroll
  for (int j = 0; j < 16; j++){
    int d = j*64 + lane;
    yv[j] = yr[d];
    dot += yv[j]*ogw[d];
  }
  for (int o = 32; o; o >>= 1) dot += __shfl_xor(dot, o);
  float s = 1.f/(1.f + __expf(-(dot + ogb[0])));
  float* outr = out + (long)n*Hc;
#pragma unroll
  for (int j = 0; j < 16; j++){
    int d = j*64 + lane;
    outr[d] = pad ? 0.f : yv[j]*s;
  }
}

__global__ void sentinel_k(float* out){ out[0] = 1.0e9f; }

// ---------------------------------------------------------------------------
extern "C" void kernel_launch(void* const* d_in, const int* in_sizes, int n_in,
                              void* d_out, int out_size, void* d_ws, size_t ws_size,
                              hipStream_t stream){
  const float* hidden  = (const float*)d_in[0];
  const int*   cnt     = (const int*)  d_in[1];
  const float* ctx_nw  = (const float*)d_in[2];
  const float* Wqkv    = (const float*)d_in[3];
  const float* in_b    = (const float*)d_in[4];
  const float* Woutp   = (const float*)d_in[5];
  const float* out_b   = (const float*)d_in[6];
  const float* gate_nw = (const float*)d_in[7];
  const float* gate_w  = (const float*)d_in[8];
  const float* exp_nw  = (const float*)d_in[9];
  const float* Weg     = (const float*)d_in[10];
  const float* Weu     = (const float*)d_in[11];
  const float* Wed     = (const float*)d_in[12];
  const float* sh_nw   = (const float*)d_in[13];
  const float* Wsg     = (const float*)d_in[14];
  const float* Wsu     = (const float*)d_in[15];
  const float* Wsd     = (const float*)d_in[16];
  const float* ogw     = (const float*)d_in[17];
  const float* ogb     = (const float*)d_in[18];
  float* out = (float*)d_out;

  const size_t MB = 1024*1024;
  char* ws = (char*)d_ws;
  size_t off = 0;
  auto alloc = [&](size_t bytes)->char*{
    char* p = ws + off; off += (bytes + 255) & ~(size_t)255; return p;
  };
  u16* wWqH  = (u16*)alloc((size_t)3072*1024*2);
  u16* wWqL  = (u16*)alloc((size_t)3072*1024*2);
  u16* wWoH  = (u16*)alloc((size_t)1024*1024*2);
  u16* wWoL  = (u16*)alloc((size_t)1024*1024*2);
  u16* wWgu  = (u16*)alloc((size_t)Ec*2*Ic*Hc*2);
  u16* wWd   = (u16*)alloc((size_t)Ec*Hc*Ic*2);
  u16* wWsgu = (u16*)alloc((size_t)2*ISc*Hc*2);
  u16* wWsd  = (u16*)alloc((size_t)Hc*ISc*2);
  int*   wTopI = (int*)  alloc((size_t)NTOK*2*4);
  float* wTopW = (float*)alloc((size_t)NTOK*2*4);
  int*   wGpos = (int*)  alloc((size_t)NTOK*2*4);
  int*   wSidx = (int*)  alloc((size_t)Ec*NTOK*4);
  float* wG    = (float*)alloc((size_t)MAXSLOTS*4);
  int*   wCnts = (int*)  alloc(64);
  int*   wOffs = (int*)  alloc(64);
  char* P1 = alloc(32*MB);
  char* P2 = alloc(32*MB);
  char* P3 = alloc(32*MB);
  char* P4 = alloc(32*MB);
  size_t fixed = off;
  const bool big = (fixed + 64*MB) <= ws_size;
  char* P5 = alloc(big ? 64*MB : 16*MB);
  if (off > ws_size){ sentinel_k<<<1,1,0,stream>>>(out); return; }

  u16*   wNx   = (u16*)P1;
  u16*   wCtx  = (u16*)P1;
  float* wY    = (float*)P1;
  u16*   wQp   = (u16*)P2;
  u16*   wXhat = (u16*)P2;
  u16*   wSx   = (u16*)(P2 + 16*MB);
  u16*   wKp   = (u16*)P3;
  float* wX    = (float*)P3;
  u16*   wGUg  = (u16*)P3;
  u16*   wZg   = (u16*)(P3 + 18*MB);
  u16*   wGUe  = (u16*)P3;
  u16*   wZe   = (u16*)(P3 + 8*MB);
  u16*   wVtp  = (u16*)P4;
  u16*   wGUs  = (u16*)P4;
  u16*   wZs   = (u16*)(P4 + 16*MB);
  float* wS    = (float*)P5;
  u16*   wD    = (u16*)P5;

  // 1) weight prep
  split_cast_k<<<4096, 256, 0, stream>>>(Wqkv,  wWqH, wWqL, (long)3072*1024);
  split_cast_k<<<2048, 256, 0, stream>>>(Woutp, wWoH, wWoL, (long)1024*1024);
  cast_bf16_k<<<2048, 256, 0, stream>>>(Wed, wWd, (long)Ec*Hc*Ic);
  cast_bf16_k<<<1024, 256, 0, stream>>>(Wsg, wWsgu,                (long)ISc*Hc);
  cast_bf16_k<<<1024, 256, 0, stream>>>(Wsu, wWsgu + (long)ISc*Hc, (long)ISc*Hc);
  cast_bf16_k<<<1024, 256, 0, stream>>>(Wsd, wWsd, (long)Hc*ISc);
  fold_expert_k<<<2048, 256, 0, stream>>>(Weg, Weu, exp_nw, wWgu, (long)Ec*Ic*Hc);

  // 2) pre-attn norm + Q&K merged projection + V projection (pad-row skip, m-XCD grid)
  rmsnorm_split_k<<<NTOK, 256, 0, stream>>>(hidden, ctx_nw, wNx);
  if (big){
    gemm3<0, 1, 3, 2><<<dim3(64, 8, 2), 256, 0, stream>>>(
        wNx, wNx + 1024, wWqH, wWqL, wQp, in_b, nullptr,
        NTOK, 1024, 1024, 2048, 1024, 2048,
        0, 0, (long)1024*1024, 0, (long)16*1024*1024, 0,
        1024, 1024, cnt, 0);
    gemm3<3, 1, 3, 2><<<dim3(64, 8, 1), 256, 0, stream>>>(
        wNx, wNx + 1024, wWqH + (long)2048*1024, wWqL + (long)2048*1024, wVtp,
        in_b + 2048, nullptr, NTOK, 1024, 1024, 2048, 1024, 0,
        0, 0, 0, 0, 0, 0, 0, 0, cnt, 0);
  } else {
    gemm3<0, 1, 0, 0><<<dim3(8, 64, 2), 256, 0, stream>>>(
        wNx, wNx + 1024, wWqH, wWqL, wQp, in_b, nullptr,
        NTOK, 1024, 1024, 2048, 1024, 2048,
        0, 0, (long)1024*1024, 0, (long)16*1024*1024, 0,
        1024, 1024, nullptr, 0);
    gemm3<3, 1, 0, 0><<<dim3(8, 64, 1), 256, 0, stream>>>(
        wNx, wNx + 1024, wWqH + (long)2048*1024, wWqL + (long)2048*1024, wVtp,
        in_b + 2048, nullptr, NTOK, 1024, 1024, 2048, 1024, 0,
        0, 0, 0, 0, 0, 0, 0, 0, nullptr, 0);
  }

  // 3) attention
  if (big){
    for (int g = 0; g < 2; g++){
      const int bbase = g*4;
      const long tokoff = (long)g*4*Lc*2048;
      const u16* Qb = wQp + tokoff;
      const u16* Kb = wKp + tokoff;
      gemm3<1, 0, 1, 1><<<dim3(8, 8, 16), 256, 0, stream>>>(
          Qb, Qb + 1024, Kb, Kb + 1024, wS, nullptr, nullptr,
          Lc, Lc, HDc, 2048, 2048, Lc,
          (long)Lc*2048, (long)HDc,
          (long)Lc*2048, (long)HDc,
          (long)Lc*Lc,   (long)4*Lc*Lc,
          0, 0, cnt, bbase);
      softmax2_k<<<16*1024, 256, 0, stream>>>(wS, cnt, bbase);
      const u16* Vb = wVtp + (long)g*4*NHc*HDc*2048;
      u16* Cb = wCtx + tokoff;
      gemm3<0, 0, 2, 1><<<dim3(2, 8, 16), 256, 0, stream>>>(
          (const u16*)wS, (const u16*)wS + 1024, Vb, Vb + 1024, Cb, nullptr, nullptr,
          Lc, HDc, Lc, 2048, 2048, 2048,
          (long)Lc*2048,     (long)4*Lc*2048,
          (long)NHc*HDc*2048,(long)HDc*2048,
          (long)Lc*2048,     (long)HDc,
          1024, 0, cnt, bbase);
    }
  } else {
    for (int g = 0; g < 8; g++){
      const int hf = g >> 2, hbase = g & 3, bbase = hf*4;
      const long tokoff = (long)hf*4*Lc*2048;
      const u16* Qb = wQp + tokoff + hbase*HDc;
      const u16* Kb = wKp + tokoff + hbase*HDc;
      gemm3<1, 0, 1, 0><<<dim3(8, 8, 4), 256, 0, stream>>>(
          Qb, Qb + 1024, Kb, Kb + 1024, wS, nullptr, nullptr,
          Lc, Lc, HDc, 2048, 2048, Lc,
          (long)Lc*2048, (long)HDc,
          (long)Lc*2048, (long)HDc,
          (long)Lc*Lc,   (long)4*Lc*Lc,
          0, 0, cnt, bbase);
      softmax2_k<<<4*1024, 256, 0, stream>>>(wS, cnt, bbase);
      const u16* Vb = wVtp + (long)hf*4*NHc*HDc*2048 + (long)hbase*HDc*2048;
      u16* Cb = wCtx + tokoff + hbase*HDc;
      gemm3<0, 0, 2, 0><<<dim3(2, 8, 4), 256, 0, stream>>>(
          (const u16*)wS, (const u16*)wS + 1024, Vb, Vb + 1024, Cb, nullptr, nullptr,
          Lc, HDc, Lc, 2048, 2048, 2048,
          (long)Lc*2048,     (long)4*Lc*2048,
          (long)NHc*HDc*2048,(long)HDc*2048,
          (long)Lc*2048,     (long)HDc,
          1024, 0, cnt, bbase);
    }
  }

  // 4) out-proj + bias + residual -> X f32 (pad-row skip, m-XCD grid)
  if (big){
    gemm3<2, 1, 3, 2><<<dim3(64, 8, 1), 256, 0, stream>>>(
        wCtx, wCtx + 1024, wWoH, wWoL, wX, out_b, hidden,
        NTOK, 1024, 1024, 2048, 1024, 1024,
        0, 0, 0, 0, 0, 0, 0, 0, cnt, 0);
  } else {
    gemm3<2, 1, 0, 0><<<dim3(8, 64, 1), 256, 0, stream>>>(
        wCtx, wCtx + 1024, wWoH, wWoL, wX, out_b, hidden,
        NTOK, 1024, 1024, 2048, 1024, 1024,
        0, 0, 0, 0, 0, 0, 0, 0, nullptr, 0);
  }

  // 5) gating (no atomics) + deterministic route build + post-norms
  gating_score_k<<<NTOK/4, 256, 0, stream>>>(wX, gate_nw, gate_w, cnt, wTopI, wTopW);
  route_scan_k<<<1, 1024, 0, stream>>>(cnt, wTopI, wTopW, wCnts, wOffs,
                                       wSidx, wGpos, wG);
  rmsnorm_k<<<NTOK, 256, 0, stream>>>(wX, wXhat, sh_nw, wSx);

  // 6) shared experts -> Y (pad-row skip, m-XCD grid)
  if (big){
    gemm_bt<0, 3, 2><<<dim3(64, 8, 1), 256, 0, stream>>>(
        wSx, wWsgu, wGUs, NTOK, 2*ISc, 1024, 1024, 1024, 2*ISc, 0, 0, 0, cnt);
    act_shared_k<<<4096, 256, 0, stream>>>(wGUs, wZs, (long)NTOK*ISc);
    gemm_bt<1, 3, 2><<<dim3(64, 8, 1), 256, 0, stream>>>(
        wZs, wWsd, wY, NTOK, 1024, ISc, ISc, ISc, 1024, 0, 0, 0, cnt);
  } else {
    gemm_bt<0, 0, 0><<<dim3(8, 64, 1), 256, 0, stream>>>(
        wSx, wWsgu, wGUs, NTOK, 2*ISc, 1024, 1024, 1024, 2*ISc, 0, 0, 0, nullptr);
    act_shared_k<<<4096, 256, 0, stream>>>(wGUs, wZs, (long)NTOK*ISc);
    gemm_bt<1, 0, 0><<<dim3(8, 64, 1), 256, 0, stream>>>(
        wZs, wWsd, wY, NTOK, 1024, ISc, ISc, ISc, 1024, 0, 0, 0, nullptr);
  }

  // 7) routed experts
  if (big){
    gemm_gu_gather<<<dim3(4, 64, Ec), 256, 0, stream>>>(
        wXhat, wWgu, wGUg, wSidx, wCnts, wOffs);
    act_slots_k<<<2048, 256, 0, stream>>>(wGUg, wG, wOffs, wZg);
    gemm_down_slots<<<dim3(8, MAXSLOTS/128, 1), 256, 0, stream>>>(
        wZg, wWd, wD, wOffs);
    final2_k<<<NTOK/4, 256, 0, stream>>>(wY, wD, wGpos, ogw, ogb, cnt, out);
  } else {
    for (int e = 0; e < Ec; e++){
      gemm_bt<0, 0, 0><<<dim3(4, 64, 1), 256, 0, stream>>>(
          wXhat, wWgu + (long)e*2*Ic*Hc, wGUe, NTOK, 2*Ic, 1024, 1024, 1024, 2*Ic,
          0, 0, 0, nullptr);
      act_expert_k<<<2048, 256, 0, stream>>>(wGUe, wTopI, wTopW, e, wZe, (long)NTOK*Ic);
      gemm_bt<2, 0, 0><<<dim3(8, 64, 1), 256, 0, stream>>>(
          wZe, wWd + (long)e*Hc*Ic, wY, NTOK, 1024, Ic, Ic, Ic, 1024, 0, 0, 0, nullptr);
    }
    final_k<<<NTOK/4, 256, 0, stream>>>(wY, ogw, ogb, cnt, out);
  }
}